// Round 14
// baseline (565.244 us; speedup 1.0000x reference)
//
#include <hip/hip_runtime.h>
#include <hip/hip_bf16.h>

typedef __bf16 bf16x8 __attribute__((ext_vector_type(8)));
typedef float  f32x4  __attribute__((ext_vector_type(4)));

#define DEVI __device__ __forceinline__

DEVI void async_copy16(const void* g, void* s) {
  __builtin_amdgcn_global_load_lds(
      (__attribute__((address_space(1))) void*)g,
      (__attribute__((address_space(3))) void*)s,
      16, 0, 0);
}

DEVI unsigned pack_bf16x2(float lo, float hi) {
  union { __hip_bfloat16 h[2]; unsigned u; } pk;
  pk.h[0] = __float2bfloat16(lo);
  pk.h[1] = __float2bfloat16(hi);
  return pk.u;
}

// ---------------------------------------------------------------------------
__global__ __launch_bounds__(256) void cvt_f32_bf16(const float* __restrict__ in,
                                                    __hip_bfloat16* __restrict__ out,
                                                    int n) {
  int i = (blockIdx.x * 256 + threadIdx.x) * 4;
  if (i >= n) return;
  float4 v = *(const float4*)(in + i);
  union { __hip_bfloat16 h[4]; ushort4 u; } o;
  o.h[0] = __float2bfloat16(v.x);
  o.h[1] = __float2bfloat16(v.y);
  o.h[2] = __float2bfloat16(v.z);
  o.h[3] = __float2bfloat16(v.w);
  *(ushort4*)(out + i) = o.u;
}

// ---------------------------------------------------------------------------
__global__ __launch_bounds__(256) void transpose_cvt(const float* __restrict__ W,
                                                     __hip_bfloat16* __restrict__ WT,
                                                     int Kdim, int Ndim) {
  __shared__ float tile[32][33];
  int bx = blockIdx.x * 32;
  int by = blockIdx.y * 32;
  int tx = threadIdx.x;
  int ty = threadIdx.y;
  #pragma unroll
  for (int j = 0; j < 32; j += 8)
    tile[ty + j][tx] = W[(size_t)(by + ty + j) * Ndim + bx + tx];
  __syncthreads();
  #pragma unroll
  for (int j = 0; j < 32; j += 8)
    WT[(size_t)(bx + ty + j) * Kdim + by + tx] = __float2bfloat16(tile[tx][ty + j]);
}

// ---------------------------------------------------------------------------
__global__ __launch_bounds__(256) void transpose_v(const __hip_bfloat16* __restrict__ vb,
                                                   __hip_bfloat16* __restrict__ vt) {
  __shared__ __hip_bfloat16 tile[32][33];
  const int s0 = blockIdx.x * 32, d0 = blockIdx.y * 32;
  const int bk = blockIdx.z;
  const int bb = bk >> 3, kvh = bk & 7;
  const int tx = threadIdx.x, ty = threadIdx.y;
  #pragma unroll
  for (int j = 0; j < 32; j += 8)
    tile[ty + j][tx] =
        vb[((size_t)(bb * 2048 + s0 + ty + j) * 8 + kvh) * 128 + d0 + tx];
  __syncthreads();
  #pragma unroll
  for (int j = 0; j < 32; j += 8)
    vt[((size_t)bk * 128 + d0 + ty + j) * 2048 + s0 + tx] = tile[tx][ty + j];
}

// ---------------------------------------------------------------------------
// 8-phase 256x256 GEMM — R12-VERIFIED schedule (explicit lgkmcnt(0)+
// sched_barrier fences; removing them doubled time in R13).
// 512 thr = 8 waves (2M x 4N), wave tile 128x64, BK=64, LDS 128KB,
// 8-slot row XOR swizzle; vmcnt(2) only at phase 0 (never drain mid-loop).
// EPI 0: f32 -> Cf.
// EPI 4: fused QKV: col<4096 -> RoPE*scale -> Cb (stride 4096);
//        col<5120 -> RoPE -> Cb2 (stride 1024); else -> Cb3 (stride 1024).
template <int EPI>
__global__ __launch_bounds__(512, 2) void gemm256(
    const __hip_bfloat16* __restrict__ A,
    const __hip_bfloat16* __restrict__ BT,
    float* __restrict__ Cf,
    __hip_bfloat16* __restrict__ Cb,
    __hip_bfloat16* __restrict__ Cb2,
    __hip_bfloat16* __restrict__ Cb3,
    int M, int N, int K,
    const float* __restrict__ fcos,
    const float* __restrict__ fsin,
    float scale) {
  __shared__ alignas(16) char lds[2][65536];
  const int tid = threadIdx.x;
  const int w = tid >> 6, l = tid & 63;
  const int l4 = l >> 4, l15 = l & 15;
  const int wr = w >> 2, wc = w & 3;      // 2M x 4N wave grid
  const int rowBase = blockIdx.y * 256;
  const int colBase = blockIdx.x * 256;

  const __hip_bfloat16* aS[2];
  const __hip_bfloat16* bS[2];
  int dstOff[2];
  #pragma unroll
  for (int i = 0; i < 2; i++) {
    int c = i * 512 + tid;
    int r = c >> 3;
    int kb = (c & 7) ^ (r & 7);
    aS[i] = A  + (size_t)(rowBase + r) * K + kb * 8;
    bS[i] = BT + (size_t)(colBase + r) * K + kb * 8;
    dstOff[i] = i * 8192 + w * 1024;     // wave-uniform; HW adds lane*16
  }
  const size_t hstep = (size_t)128 * K;  // +128 rows

  f32x4 acc[8][4];
  #pragma unroll
  for (int mi = 0; mi < 8; mi++)
    #pragma unroll
    for (int ni = 0; ni < 4; ni++)
      acc[mi][ni] = (f32x4){0.f, 0.f, 0.f, 0.f};

  // prologue: stage K-tile 0 -> buf0
  #pragma unroll
  for (int i = 0; i < 2; i++) async_copy16(aS[i],         lds[0] + 0     + dstOff[i]);
  #pragma unroll
  for (int i = 0; i < 2; i++) async_copy16(aS[i] + hstep, lds[0] + 16384 + dstOff[i]);
  #pragma unroll
  for (int i = 0; i < 2; i++) async_copy16(bS[i],         lds[0] + 32768 + dstOff[i]);
  #pragma unroll
  for (int i = 0; i < 2; i++) async_copy16(bS[i] + hstep, lds[0] + 49152 + dstOff[i]);

  const int NT = K >> 6;
  const int pswz = l15 & 7;              // read-side row-XOR component
  bf16x8 bF[4][2];

  for (int kt = 0; kt < NT; kt++) {
    const char* bufc = lds[kt & 1];
    char* bufn = lds[(kt & 1) ^ 1];
    const int koff = (kt + 1) * 64;
    const bool pre = (kt + 1 < NT);

    // ---------------- phase 0 ----------------
    if (pre) {
      #pragma unroll
      for (int i = 0; i < 2; i++) async_copy16(aS[i] + koff, bufn + 0 + dstOff[i]);
    }
    if (pre) { asm volatile("s_waitcnt vmcnt(2)" ::: "memory"); }
    else     { asm volatile("s_waitcnt vmcnt(0)" ::: "memory"); }
    __builtin_amdgcn_s_barrier();        // K-tile kt visible to all waves
    __builtin_amdgcn_sched_barrier(0);

    // all B frags (8 reads) + A frags mi=0,1 (4 reads)
    #pragma unroll
    for (int ni = 0; ni < 4; ni++)
      #pragma unroll
      for (int kh = 0; kh < 2; kh++) {
        int R = wc * 64 + ni * 16 + l15;
        int phys = (kh * 4 + l4) ^ pswz;
        bF[ni][kh] = *(const bf16x8*)(bufc + 32768 + (R >> 7) * 16384 +
                                      (R & 127) * 128 + phys * 16);
      }
    {
      bf16x8 aF[2][2];
      #pragma unroll
      for (int f = 0; f < 2; f++)
        #pragma unroll
        for (int kh = 0; kh < 2; kh++) {
          int lr = f * 16 + l15;
          int phys = (kh * 4 + l4) ^ pswz;
          aF[f][kh] = *(const bf16x8*)(bufc + wr * 16384 + lr * 128 + phys * 16);
        }
      asm volatile("s_waitcnt lgkmcnt(0)" ::: "memory");
      __builtin_amdgcn_sched_barrier(0);
      __builtin_amdgcn_s_setprio(1);
      #pragma unroll
      for (int f = 0; f < 2; f++)
        #pragma unroll
        for (int ni = 0; ni < 4; ni++)
          #pragma unroll
          for (int kh = 0; kh < 2; kh++)
            acc[f][ni] = __builtin_amdgcn_mfma_f32_16x16x32_bf16(
                aF[f][kh], bF[ni][kh], acc[f][ni], 0, 0, 0);
      __builtin_amdgcn_s_setprio(0);
    }
    __builtin_amdgcn_s_barrier();

    // ---------------- phases 1..3 ----------------
    #pragma unroll
    for (int p = 1; p < 4; p++) {
      bf16x8 aF[2][2];
      #pragma unroll
      for (int f = 0; f < 2; f++)
        #pragma unroll
        for (int kh = 0; kh < 2; kh++) {
          int lr = (2 * p + f) * 16 + l15;
          int phys = (kh * 4 + l4) ^ pswz;
          aF[f][kh] = *(const bf16x8*)(bufc + wr * 16384 + lr * 128 + phys * 16);
        }
      if (pre) {
        if (p == 1) {
          #pragma unroll
          for (int i = 0; i < 2; i++)
            async_copy16(aS[i] + hstep + koff, bufn + 16384 + dstOff[i]);
        } else if (p == 2) {
          #pragma unroll
          for (int i = 0; i < 2; i++)
            async_copy16(bS[i] + koff, bufn + 32768 + dstOff[i]);
        } else {
          #pragma unroll
          for (int i = 0; i < 2; i++)
            async_copy16(bS[i] + hstep + koff, bufn + 49152 + dstOff[i]);
        }
      }
      __builtin_amdgcn_s_barrier();
      asm volatile("s_waitcnt lgkmcnt(0)" ::: "memory");
      __builtin_amdgcn_sched_barrier(0);
      __builtin_amdgcn_s_setprio(1);
      #pragma unroll
      for (int f = 0; f < 2; f++)
        #pragma unroll
        for (int ni = 0; ni < 4; ni++)
          #pragma unroll
          for (int kh = 0; kh < 2; kh++)
            acc[2 * p + f][ni] = __builtin_amdgcn_mfma_f32_16x16x32_bf16(
                aF[f][kh], bF[ni][kh], acc[2 * p + f][ni], 0, 0, 0);
      __builtin_amdgcn_s_setprio(0);
      __builtin_amdgcn_s_barrier();
    }
  }

  // epilogue
  const int orow0 = rowBase + wr * 128 + l4 * 4;
  const int ocol0 = colBase + wc * 64 + l15;
  #pragma unroll
  for (int mi = 0; mi < 8; mi++) {
    #pragma unroll
    for (int ni = 0; ni < 4; ni++) {
      #pragma unroll
      for (int reg = 0; reg < 4; reg++) {
        int r = orow0 + mi * 16 + reg;
        int col = ocol0 + ni * 16;
        float v = acc[mi][ni][reg];
        if constexpr (EPI == 0) {
          Cf[(size_t)r * N + col] = v;
        } else {
          if (colBase < 4096) {          // Q: RoPE * qscale
            float p2 = __shfl_xor(v, 1);
            int fi = (col & 127) >> 1;
            int srow = r & 2047;
            float c = fcos[srow * 64 + fi];
            float s = fsin[srow * 64 + fi];
            float outv = ((col & 1) == 0) ? (v * c - p2 * s) : (p2 * s + v * c);
            Cb[(size_t)r * 4096 + col] = __float2bfloat16(outv * scale);
          } else if (colBase < 5120) {   // K: RoPE
            float p2 = __shfl_xor(v, 1);
            int fi = (col & 127) >> 1;
            int srow = r & 2047;
            float c = fcos[srow * 64 + fi];
            float s = fsin[srow * 64 + fi];
            float outv = ((col & 1) == 0) ? (v * c - p2 * s) : (p2 * s + v * c);
            Cb2[(size_t)r * 1024 + (col - 4096)] = __float2bfloat16(outv);
          } else {                       // V: plain
            Cb3[(size_t)r * 1024 + (col - 5120)] = __float2bfloat16(v);
          }
        }
      }
    }
  }
}

// ---------------------------------------------------------------------------
// flash attention v6 (unchanged, verified): qt-paired blocks, QBLK=128,
// KVBLK=64, swapped QK^T, in-lane softmax, 2-phase dbuf, setprio.
__global__ __launch_bounds__(256, 2) void attn_kernel(
    const __hip_bfloat16* __restrict__ Q,
    const __hip_bfloat16* __restrict__ Kb,
    const __hip_bfloat16* __restrict__ Vt_g,
    __hip_bfloat16* __restrict__ O) {
  const int S = 2048, HD = 4096, KVD = 1024, D = 128;
  const int h = blockIdx.y, b = blockIdx.z;
  const int kvh = h >> 2;
  const int bk = b * 8 + kvh;
  const int tid = threadIdx.x;
  const int w = tid >> 6, l = tid & 63;
  const int l4 = l >> 4, l15 = l & 15;

  __shared__ alignas(16) __hip_bfloat16 Kt[2][64 * 128];
  __shared__ alignas(16) __hip_bfloat16 Vt[2][128 * 64];
  __shared__ alignas(16) __hip_bfloat16 Pb[4 * 32 * 64];

  const __hip_bfloat16* kSrc[4];
  const __hip_bfloat16* vSrc[4];
  int stDst[4];
  #pragma unroll
  for (int i = 0; i < 4; i++) {
    int c = i * 256 + tid;
    int kr = c >> 4;
    int kds = (c & 15) ^ (kr & 7);
    kSrc[i] = Kb + (size_t)(b * S + kr) * KVD + kvh * D + kds * 8;
    int vr = c >> 3;
    int vds = (c & 7) ^ (vr & 7);
    vSrc[i] = Vt_g + ((size_t)bk * 128 + vr) * 2048 + vds * 8;
    stDst[i] = (i * 256 + w * 64) * 16;
  }

  char* pbase = (char*)Pb + w * 4096;

  for (int pass = 0; pass < 2; pass++) {
    const int qt = pass ? (15 - blockIdx.x) : blockIdx.x;
    const int qbase = qt * 128 + w * 32;
    const int nt = 2 * qt + 2;

    bf16x8 qf[2][4];
    #pragma unroll
    for (int f = 0; f < 2; f++) {
      const int qrow = qbase + f * 16 + l15;
      const __hip_bfloat16* qptr = Q + (size_t)(b * S + qrow) * HD + h * D + l4 * 8;
      #pragma unroll
      for (int dc = 0; dc < 4; dc++) qf[f][dc] = *(const bf16x8*)(qptr + dc * 32);
    }

    f32x4 o[2][8];
    #pragma unroll
    for (int f = 0; f < 2; f++)
      #pragma unroll
      for (int nf = 0; nf < 8; nf++) o[f][nf] = (f32x4){0.f, 0.f, 0.f, 0.f};
    float mrun[2]  = {-1e30f, -1e30f};
    float llrun[2] = {0.f, 0.f};

    if (pass) __syncthreads();

    #pragma unroll
    for (int i = 0; i < 4; i++) {
      async_copy16(kSrc[i], (char*)Kt + stDst[i]);
      async_copy16(vSrc[i], (char*)Vt + stDst[i]);
    }

    int cur = 0;
    for (int t = 0; t < nt; t++) {
      __syncthreads();
      if (t + 1 < nt) {
        const int kv1 = (t + 1) * 64;
        #pragma unroll
        for (int i = 0; i < 4; i++) {
          async_copy16(kSrc[i] + (size_t)kv1 * KVD, (char*)Kt + (cur ^ 1) * 16384 + stDst[i]);
          async_copy16(vSrc[i] + kv1,               (char*)Vt + (cur ^ 1) * 16384 + stDst[i]);
        }
      }
      const char* ktb = (const char*)Kt + cur * 16384;
      const char* vtb = (const char*)Vt + cur * 16384;
      const int kv0 = t * 64;

      f32x4 s[2][4];
      #pragma unroll
      for (int f = 0; f < 2; f++)
        #pragma unroll
        for (int kg = 0; kg < 4; kg++) s[f][kg] = (f32x4){0.f, 0.f, 0.f, 0.f};
      __builtin_amdgcn_s_setprio(1);
      #pragma unroll
      for (int dc = 0; dc < 4; dc++) {
        #pragma unroll
        for (int kg = 0; kg < 4; kg++) {
          int key = kg * 16 + l15;
          int phys = (dc * 4 + l4) ^ (key & 7);
          bf16x8 kf = *(const bf16x8*)(ktb + key * 256 + phys * 16);
          s[0][kg] = __builtin_amdgcn_mfma_f32_16x16x32_bf16(kf, qf[0][dc], s[0][kg], 0, 0, 0);
          s[1][kg] = __builtin_amdgcn_mfma_f32_16x16x32_bf16(kf, qf[1][dc], s[1][kg], 0, 0, 0);
        }
      }
      __builtin_amdgcn_s_setprio(0);

      if (t >= nt - 2) {
        #pragma unroll
        for (int f = 0; f < 2; f++) {
          int q = qbase + f * 16 + l15;
          #pragma unroll
          for (int kg = 0; kg < 4; kg++)
            #pragma unroll
            for (int reg = 0; reg < 4; reg++)
              if (kv0 + kg * 16 + 4 * l4 + reg > q) s[f][kg][reg] = -1e30f;
        }
      }

      #pragma unroll
      for (int f = 0; f < 2; f++) {
        float pmax = -1e30f;
        #pragma unroll
        for (int kg = 0; kg < 4; kg++)
          #pragma unroll
          for (int reg = 0; reg < 4; reg++) pmax = fmaxf(pmax, s[f][kg][reg]);
        pmax = fmaxf(pmax, __shfl_xor(pmax, 16));
        pmax = fmaxf(pmax, __shfl_xor(pmax, 32));
        float mn = fmaxf(mrun[f], pmax);
        float alpha = __expf(mrun[f] - mn);
        mrun[f] = mn;
        float rs = 0.f;
        #pragma unroll
        for (int kg = 0; kg < 4; kg++)
          #pragma unroll
          for (int reg = 0; reg < 4; reg++) {
            float p = __expf(s[f][kg][reg] - mn);
            s[f][kg][reg] = p;
            rs += p;
          }
        rs += __shfl_xor(rs, 16);
        rs += __shfl_xor(rs, 32);
        llrun[f] = llrun[f] * alpha + rs;

        #pragma unroll
        for (int kg = 0; kg < 4; kg++)
          #pragma unroll
          for (int p2 = 0; p2 < 2; p2++) {
            unsigned u = pack_bf16x2(s[f][kg][2 * p2], s[f][kg][2 * p2 + 1]);
            int slot16 = 2 * kg + (l4 >> 1);
            int inner = (8 * l4 + 4 * p2) & 15;
            *(unsigned*)(pbase + (f * 16 + l15) * 128 + ((slot16 ^ (l15 & 7)) * 16) + inner) = u;
          }

        float alpha_r[4];
        #pragma unroll
        for (int reg = 0; reg < 4; reg++)
          alpha_r[reg] = __shfl(alpha, (l & 48) + 4 * l4 + reg);
        #pragma unroll
        for (int nf = 0; nf < 8; nf++)
          #pragma unroll
          for (int reg = 0; reg < 4; reg++) o[f][nf][reg] *= alpha_r[reg];
      }

      __builtin_amdgcn_s_setprio(1);
      #pragma unroll
      for (int half = 0; half < 2; half++) {
        int physp = (half * 4 + l4) ^ (l15 & 7);
        bf16x8 pa0 = *(const bf16x8*)(pbase + (0 * 16 + l15) * 128 + physp * 16);
        bf16x8 pa1 = *(const bf16x8*)(pbase + (1 * 16 + l15) * 128 + physp * 16);
        #pragma unroll
        for (int nf = 0; nf < 8; nf++) {
          int d = nf * 16 + l15;
          bf16x8 vf = *(const bf16x8*)(vtb + d * 128 + physp * 16);
          o[0][nf] = __builtin_amdgcn_mfma_f32_16x16x32_bf16(pa0, vf, o[0][nf], 0, 0, 0);
          o[1][nf] = __builtin_amdgcn_mfma_f32_16x16x32_bf16(pa1, vf, o[1][nf], 0, 0, 0);
        }
      }
      __builtin_amdgcn_s_setprio(0);
      cur ^= 1;
    }

    #pragma unroll
    for (int f = 0; f < 2; f++) {
      #pragma unroll
      for (int reg = 0; reg < 4; reg++) {
        float llr = __shfl(llrun[f], (l & 48) + 4 * l4 + reg);
        float inv = 1.0f / llr;
        int r = qbase + f * 16 + 4 * l4 + reg;
        __hip_bfloat16* optr = O + (size_t)(b * S + r) * HD + h * D + l15;
        #pragma unroll
        for (int nf = 0; nf < 8; nf++) optr[nf * 16] = __float2bfloat16(o[f][nf][reg] * inv);
      }
    }
  }
}

// ---------------------------------------------------------------------------
extern "C" void kernel_launch(void* const* d_in, const int* in_sizes, int n_in,
                              void* d_out, int out_size, void* d_ws, size_t ws_size,
                              hipStream_t stream) {
  const float* x    = (const float*)d_in[0];
  const float* fcos = (const float*)d_in[2];
  const float* fsin = (const float*)d_in[3];
  const float* wq   = (const float*)d_in[5];
  const float* wk   = (const float*)d_in[6];
  const float* wv   = (const float*)d_in[7];
  const float* wo   = (const float*)d_in[8];
  float* out = (float*)d_out;

  char* ws = (char*)d_ws;
  const size_t MB = 1024 * 1024;
  __hip_bfloat16* xb  = (__hip_bfloat16*)(ws + 0);        // 32MB; reused as ab
  __hip_bfloat16* wT  = (__hip_bfloat16*)(ws + 32 * MB);  // wqT (32MB); then vt; then woT
  __hip_bfloat16* wkT = (__hip_bfloat16*)(ws + 64 * MB);  // 8MB, contiguous after wqT
  __hip_bfloat16* wvT = (__hip_bfloat16*)(ws + 72 * MB);  // 8MB, contiguous after wkT
  __hip_bfloat16* qb  = (__hip_bfloat16*)(ws + 80 * MB);
  __hip_bfloat16* kb  = (__hip_bfloat16*)(ws + 112 * MB);
  __hip_bfloat16* vb  = (__hip_bfloat16*)(ws + 120 * MB);
  __hip_bfloat16* ab  = xb;
  __hip_bfloat16* vt  = wT;

  const float qscale = 0.08838834764831845f;  // 1/sqrt(128)

  cvt_f32_bf16<<<16384, 256, 0, stream>>>(x, xb, 16777216);
  transpose_cvt<<<dim3(128, 128), dim3(32, 8), 0, stream>>>(wq, wT, 4096, 4096);
  transpose_cvt<<<dim3(32, 128), dim3(32, 8), 0, stream>>>(wk, wkT, 4096, 1024);
  transpose_cvt<<<dim3(32, 128), dim3(32, 8), 0, stream>>>(wv, wvT, 4096, 1024);

  // fused Q+K+V projection: BT = [wqT ; wkT ; wvT] contiguous, N=6144
  gemm256<4><<<dim3(24, 16), 512, 0, stream>>>(xb, wT, nullptr, qb, kb, vb,
                                               4096, 6144, 4096, fcos, fsin, qscale);

  transpose_v<<<dim3(64, 4, 16), dim3(32, 8), 0, stream>>>(vb, vt);

  attn_kernel<<<dim3(8, 32, 2), 256, 0, stream>>>(qb, kb, vt, ab);

  transpose_cvt<<<dim3(128, 128), dim3(32, 8), 0, stream>>>(wo, wT, 4096, 4096);
  gemm256<0><<<dim3(16, 16), 512, 0, stream>>>(ab, wT, out, nullptr, nullptr, nullptr,
                                               4096, 4096, 4096, nullptr, nullptr, 1.0f);
}

// Round 15
// 536.161 us; speedup vs baseline: 1.0542x; 1.0542x over previous
//
#include <hip/hip_runtime.h>
#include <hip/hip_bf16.h>

typedef __bf16 bf16x8 __attribute__((ext_vector_type(8)));
typedef float  f32x4  __attribute__((ext_vector_type(4)));

#define DEVI __device__ __forceinline__

DEVI void async_copy16(const void* g, void* s) {
  __builtin_amdgcn_global_load_lds(
      (__attribute__((address_space(1))) void*)g,
      (__attribute__((address_space(3))) void*)s,
      16, 0, 0);
}

DEVI unsigned pack_bf16x2(float lo, float hi) {
  union { __hip_bfloat16 h[2]; unsigned u; } pk;
  pk.h[0] = __float2bfloat16(lo);
  pk.h[1] = __float2bfloat16(hi);
  return pk.u;
}

// ---------------------------------------------------------------------------
__global__ __launch_bounds__(256) void cvt_f32_bf16(const float* __restrict__ in,
                                                    __hip_bfloat16* __restrict__ out,
                                                    int n) {
  int i = (blockIdx.x * 256 + threadIdx.x) * 4;
  if (i >= n) return;
  float4 v = *(const float4*)(in + i);
  union { __hip_bfloat16 h[4]; ushort4 u; } o;
  o.h[0] = __float2bfloat16(v.x);
  o.h[1] = __float2bfloat16(v.y);
  o.h[2] = __float2bfloat16(v.z);
  o.h[3] = __float2bfloat16(v.w);
  *(ushort4*)(out + i) = o.u;
}

// ---------------------------------------------------------------------------
__global__ __launch_bounds__(256) void transpose_cvt(const float* __restrict__ W,
                                                     __hip_bfloat16* __restrict__ WT,
                                                     int Kdim, int Ndim) {
  __shared__ float tile[32][33];
  int bx = blockIdx.x * 32;
  int by = blockIdx.y * 32;
  int tx = threadIdx.x;
  int ty = threadIdx.y;
  #pragma unroll
  for (int j = 0; j < 32; j += 8)
    tile[ty + j][tx] = W[(size_t)(by + ty + j) * Ndim + bx + tx];
  __syncthreads();
  #pragma unroll
  for (int j = 0; j < 32; j += 8)
    WT[(size_t)(bx + ty + j) * Kdim + by + tx] = __float2bfloat16(tile[tx][ty + j]);
}

// ---------------------------------------------------------------------------
__global__ __launch_bounds__(256) void transpose_v(const __hip_bfloat16* __restrict__ vb,
                                                   __hip_bfloat16* __restrict__ vt) {
  __shared__ __hip_bfloat16 tile[32][33];
  const int s0 = blockIdx.x * 32, d0 = blockIdx.y * 32;
  const int bk = blockIdx.z;
  const int bb = bk >> 3, kvh = bk & 7;
  const int tx = threadIdx.x, ty = threadIdx.y;
  #pragma unroll
  for (int j = 0; j < 32; j += 8)
    tile[ty + j][tx] =
        vb[((size_t)(bb * 2048 + s0 + ty + j) * 8 + kvh) * 128 + d0 + tx];
  __syncthreads();
  #pragma unroll
  for (int j = 0; j < 32; j += 8)
    vt[((size_t)bk * 128 + d0 + ty + j) * 2048 + s0 + tx] = tile[tx][ty + j];
}

// ---------------------------------------------------------------------------
// 8-phase 256x256 GEMM — R12-verified schedule. 128KB LDS -> 1 block/CU, so
// GRID MUST BE <= 256 BLOCKS AND A MULTIPLE OF THE ROUND (R13/R14 lesson:
// 384 blocks = 1.5 rounds -> second round half-idle -> 2x time).
// EPI 0: f32 -> Cf.  EPI 4: col<4096 -> RoPE*scale -> Cb (stride 4096);
// col<5120 -> RoPE -> Cb2; else -> Cb3 (used with N=4096 => Q branch only).
template <int EPI>
__global__ __launch_bounds__(512, 2) void gemm256(
    const __hip_bfloat16* __restrict__ A,
    const __hip_bfloat16* __restrict__ BT,
    float* __restrict__ Cf,
    __hip_bfloat16* __restrict__ Cb,
    __hip_bfloat16* __restrict__ Cb2,
    __hip_bfloat16* __restrict__ Cb3,
    int M, int N, int K,
    const float* __restrict__ fcos,
    const float* __restrict__ fsin,
    float scale) {
  __shared__ alignas(16) char lds[2][65536];
  const int tid = threadIdx.x;
  const int w = tid >> 6, l = tid & 63;
  const int l4 = l >> 4, l15 = l & 15;
  const int wr = w >> 2, wc = w & 3;      // 2M x 4N wave grid
  const int rowBase = blockIdx.y * 256;
  const int colBase = blockIdx.x * 256;

  const __hip_bfloat16* aS[2];
  const __hip_bfloat16* bS[2];
  int dstOff[2];
  #pragma unroll
  for (int i = 0; i < 2; i++) {
    int c = i * 512 + tid;
    int r = c >> 3;
    int kb = (c & 7) ^ (r & 7);
    aS[i] = A  + (size_t)(rowBase + r) * K + kb * 8;
    bS[i] = BT + (size_t)(colBase + r) * K + kb * 8;
    dstOff[i] = i * 8192 + w * 1024;     // wave-uniform; HW adds lane*16
  }
  const size_t hstep = (size_t)128 * K;  // +128 rows

  f32x4 acc[8][4];
  #pragma unroll
  for (int mi = 0; mi < 8; mi++)
    #pragma unroll
    for (int ni = 0; ni < 4; ni++)
      acc[mi][ni] = (f32x4){0.f, 0.f, 0.f, 0.f};

  // prologue: stage K-tile 0 -> buf0
  #pragma unroll
  for (int i = 0; i < 2; i++) async_copy16(aS[i],         lds[0] + 0     + dstOff[i]);
  #pragma unroll
  for (int i = 0; i < 2; i++) async_copy16(aS[i] + hstep, lds[0] + 16384 + dstOff[i]);
  #pragma unroll
  for (int i = 0; i < 2; i++) async_copy16(bS[i],         lds[0] + 32768 + dstOff[i]);
  #pragma unroll
  for (int i = 0; i < 2; i++) async_copy16(bS[i] + hstep, lds[0] + 49152 + dstOff[i]);

  const int NT = K >> 6;
  const int pswz = l15 & 7;              // read-side row-XOR component
  bf16x8 bF[4][2];

  for (int kt = 0; kt < NT; kt++) {
    const char* bufc = lds[kt & 1];
    char* bufn = lds[(kt & 1) ^ 1];
    const int koff = (kt + 1) * 64;
    const bool pre = (kt + 1 < NT);

    // ---------------- phase 0 ----------------
    if (pre) {
      #pragma unroll
      for (int i = 0; i < 2; i++) async_copy16(aS[i] + koff, bufn + 0 + dstOff[i]);
    }
    if (pre) { asm volatile("s_waitcnt vmcnt(2)" ::: "memory"); }
    else     { asm volatile("s_waitcnt vmcnt(0)" ::: "memory"); }
    __builtin_amdgcn_s_barrier();        // K-tile kt visible to all waves
    __builtin_amdgcn_sched_barrier(0);

    // all B frags (8 reads) + A frags mi=0,1 (4 reads)
    #pragma unroll
    for (int ni = 0; ni < 4; ni++)
      #pragma unroll
      for (int kh = 0; kh < 2; kh++) {
        int R = wc * 64 + ni * 16 + l15;
        int phys = (kh * 4 + l4) ^ pswz;
        bF[ni][kh] = *(const bf16x8*)(bufc + 32768 + (R >> 7) * 16384 +
                                      (R & 127) * 128 + phys * 16);
      }
    {
      bf16x8 aF[2][2];
      #pragma unroll
      for (int f = 0; f < 2; f++)
        #pragma unroll
        for (int kh = 0; kh < 2; kh++) {
          int lr = f * 16 + l15;
          int phys = (kh * 4 + l4) ^ pswz;
          aF[f][kh] = *(const bf16x8*)(bufc + wr * 16384 + lr * 128 + phys * 16);
        }
      asm volatile("s_waitcnt lgkmcnt(0)" ::: "memory");
      __builtin_amdgcn_sched_barrier(0);
      __builtin_amdgcn_s_setprio(1);
      #pragma unroll
      for (int f = 0; f < 2; f++)
        #pragma unroll
        for (int ni = 0; ni < 4; ni++)
          #pragma unroll
          for (int kh = 0; kh < 2; kh++)
            acc[f][ni] = __builtin_amdgcn_mfma_f32_16x16x32_bf16(
                aF[f][kh], bF[ni][kh], acc[f][ni], 0, 0, 0);
      __builtin_amdgcn_s_setprio(0);
    }
    __builtin_amdgcn_s_barrier();

    // ---------------- phases 1..3 ----------------
    #pragma unroll
    for (int p = 1; p < 4; p++) {
      bf16x8 aF[2][2];
      #pragma unroll
      for (int f = 0; f < 2; f++)
        #pragma unroll
        for (int kh = 0; kh < 2; kh++) {
          int lr = (2 * p + f) * 16 + l15;
          int phys = (kh * 4 + l4) ^ pswz;
          aF[f][kh] = *(const bf16x8*)(bufc + wr * 16384 + lr * 128 + phys * 16);
        }
      if (pre) {
        if (p == 1) {
          #pragma unroll
          for (int i = 0; i < 2; i++)
            async_copy16(aS[i] + hstep + koff, bufn + 16384 + dstOff[i]);
        } else if (p == 2) {
          #pragma unroll
          for (int i = 0; i < 2; i++)
            async_copy16(bS[i] + koff, bufn + 32768 + dstOff[i]);
        } else {
          #pragma unroll
          for (int i = 0; i < 2; i++)
            async_copy16(bS[i] + hstep + koff, bufn + 49152 + dstOff[i]);
        }
      }
      __builtin_amdgcn_s_barrier();
      asm volatile("s_waitcnt lgkmcnt(0)" ::: "memory");
      __builtin_amdgcn_sched_barrier(0);
      __builtin_amdgcn_s_setprio(1);
      #pragma unroll
      for (int f = 0; f < 2; f++)
        #pragma unroll
        for (int ni = 0; ni < 4; ni++)
          #pragma unroll
          for (int kh = 0; kh < 2; kh++)
            acc[2 * p + f][ni] = __builtin_amdgcn_mfma_f32_16x16x32_bf16(
                aF[f][kh], bF[ni][kh], acc[2 * p + f][ni], 0, 0, 0);
      __builtin_amdgcn_s_setprio(0);
      __builtin_amdgcn_s_barrier();
    }
  }

  // epilogue
  const int orow0 = rowBase + wr * 128 + l4 * 4;
  const int ocol0 = colBase + wc * 64 + l15;
  #pragma unroll
  for (int mi = 0; mi < 8; mi++) {
    #pragma unroll
    for (int ni = 0; ni < 4; ni++) {
      #pragma unroll
      for (int reg = 0; reg < 4; reg++) {
        int r = orow0 + mi * 16 + reg;
        int col = ocol0 + ni * 16;
        float v = acc[mi][ni][reg];
        if constexpr (EPI == 0) {
          Cf[(size_t)r * N + col] = v;
        } else {
          if (colBase < 4096) {          // Q: RoPE * qscale
            float p2 = __shfl_xor(v, 1);
            int fi = (col & 127) >> 1;
            int srow = r & 2047;
            float c = fcos[srow * 64 + fi];
            float s = fsin[srow * 64 + fi];
            float outv = ((col & 1) == 0) ? (v * c - p2 * s) : (p2 * s + v * c);
            Cb[(size_t)r * 4096 + col] = __float2bfloat16(outv * scale);
          } else if (colBase < 5120) {   // K: RoPE
            float p2 = __shfl_xor(v, 1);
            int fi = (col & 127) >> 1;
            int srow = r & 2047;
            float c = fcos[srow * 64 + fi];
            float s = fsin[srow * 64 + fi];
            float outv = ((col & 1) == 0) ? (v * c - p2 * s) : (p2 * s + v * c);
            Cb2[(size_t)r * 1024 + (col - 4096)] = __float2bfloat16(outv);
          } else {                       // V: plain
            Cb3[(size_t)r * 1024 + (col - 5120)] = __float2bfloat16(v);
          }
        }
      }
    }
  }
}

// ---------------------------------------------------------------------------
// 128x128 GEMM, 3-buffer 1-barrier pipeline (R11-verified, 84 us for KV).
// EPI 3: fused KV: col<1024 -> RoPE -> Cb; col>=1024 -> Cb2 (both stride 1024)
template <int EPI>
__global__ __launch_bounds__(256) void gemm_bt(
    const __hip_bfloat16* __restrict__ A,
    const __hip_bfloat16* __restrict__ BT,
    float* __restrict__ Cf,
    __hip_bfloat16* __restrict__ Cb,
    __hip_bfloat16* __restrict__ Cb2,
    int M, int N, int K,
    const float* __restrict__ fcos,
    const float* __restrict__ fsin,
    float scale) {
  __shared__ alignas(16) __hip_bfloat16 lds[3][8192];
  const int tid = threadIdx.x;
  const int w = tid >> 6, l = tid & 63;
  const int l4 = l >> 4, l15 = l & 15;
  const int wr = w >> 1, wc = w & 1;
  const int rowBase = blockIdx.y * 128;
  const int colBase = blockIdx.x * 128;

  const __hip_bfloat16* aSrc[2];
  const __hip_bfloat16* bSrc[2];
  int dstOff[2];
  #pragma unroll
  for (int i = 0; i < 2; i++) {
    int c = i * 256 + tid;
    int r = c >> 2;
    int kb = (c & 3) ^ ((r >> 1) & 3);
    aSrc[i] = A  + (size_t)(rowBase + r) * K + kb * 8;
    bSrc[i] = BT + (size_t)(colBase + r) * K + kb * 8;
    dstOff[i] = (i * 256 + w * 64) * 16;
  }

  f32x4 acc[4][4];
  #pragma unroll
  for (int mi = 0; mi < 4; mi++)
    #pragma unroll
    for (int ni = 0; ni < 4; ni++)
      acc[mi][ni] = (f32x4){0.f, 0.f, 0.f, 0.f};

  #pragma unroll
  for (int i = 0; i < 2; i++) {
    async_copy16(aSrc[i], (char*)lds + dstOff[i]);
    async_copy16(bSrc[i], (char*)lds + 8192 + dstOff[i]);
  }
  #pragma unroll
  for (int i = 0; i < 2; i++) {
    async_copy16(aSrc[i] + 32, (char*)lds + 16384 + dstOff[i]);
    async_copy16(bSrc[i] + 32, (char*)lds + 16384 + 8192 + dstOff[i]);
  }

  int cur = 0;
  for (int k0 = 0; k0 < K; k0 += 32) {
    if (k0 + 32 < K) {
      asm volatile("s_waitcnt vmcnt(4)" ::: "memory");
    } else {
      asm volatile("s_waitcnt vmcnt(0)" ::: "memory");
    }
    __builtin_amdgcn_s_barrier();
    __builtin_amdgcn_sched_barrier(0);

    const char* base = (const char*)lds + cur * 16384;
    bf16x8 aF[4], bF[4];
    #pragma unroll
    for (int mi = 0; mi < 4; mi++) {
      int row = wr * 64 + mi * 16 + l15;
      int phys = l4 ^ ((row >> 1) & 3);
      aF[mi] = *(const bf16x8*)(base + row * 64 + phys * 16);
    }
    #pragma unroll
    for (int ni = 0; ni < 4; ni++) {
      int row = wc * 64 + ni * 16 + l15;
      int phys = l4 ^ ((row >> 1) & 3);
      bF[ni] = *(const bf16x8*)(base + 8192 + row * 64 + phys * 16);
    }
    asm volatile("s_waitcnt lgkmcnt(0)" ::: "memory");
    __builtin_amdgcn_sched_barrier(0);

    if (k0 + 64 < K) {
      int nxt = cur + 2; if (nxt >= 3) nxt -= 3;
      #pragma unroll
      for (int i = 0; i < 2; i++) {
        async_copy16(aSrc[i] + k0 + 64, (char*)lds + nxt * 16384 + dstOff[i]);
        async_copy16(bSrc[i] + k0 + 64, (char*)lds + nxt * 16384 + 8192 + dstOff[i]);
      }
    }

    __builtin_amdgcn_s_setprio(1);
    #pragma unroll
    for (int mi = 0; mi < 4; mi++)
      #pragma unroll
      for (int ni = 0; ni < 4; ni++)
        acc[mi][ni] = __builtin_amdgcn_mfma_f32_16x16x32_bf16(aF[mi], bF[ni], acc[mi][ni], 0, 0, 0);
    __builtin_amdgcn_s_setprio(0);
    cur = (cur + 1 == 3) ? 0 : cur + 1;
  }

  const int orow0 = rowBase + wr * 64 + l4 * 4;
  const int ocol0 = colBase + wc * 64 + l15;
  #pragma unroll
  for (int mi = 0; mi < 4; mi++) {
    #pragma unroll
    for (int ni = 0; ni < 4; ni++) {
      #pragma unroll
      for (int reg = 0; reg < 4; reg++) {
        int r = orow0 + mi * 16 + reg;
        int col = ocol0 + ni * 16;
        float v = acc[mi][ni][reg];
        if constexpr (EPI == 0) {
          Cf[(size_t)r * N + col] = v;
        } else if constexpr (EPI == 3) {
          if (colBase < 1024) {
            float p = __shfl_xor(v, 1);
            int fi = (col & 127) >> 1;
            int srow = r & 2047;
            float c = fcos[srow * 64 + fi];
            float s = fsin[srow * 64 + fi];
            float outv = ((col & 1) == 0) ? (v * c - p * s) : (p * s + v * c);
            Cb[(size_t)r * 1024 + col] = __float2bfloat16(outv);
          } else {
            Cb2[(size_t)r * 1024 + (col - 1024)] = __float2bfloat16(v);
          }
        }
      }
    }
  }
}

// ---------------------------------------------------------------------------
// flash attention v6 (unchanged, verified): qt-paired blocks, QBLK=128,
// KVBLK=64, swapped QK^T, in-lane softmax, 2-phase dbuf, setprio.
__global__ __launch_bounds__(256, 2) void attn_kernel(
    const __hip_bfloat16* __restrict__ Q,
    const __hip_bfloat16* __restrict__ Kb,
    const __hip_bfloat16* __restrict__ Vt_g,
    __hip_bfloat16* __restrict__ O) {
  const int S = 2048, HD = 4096, KVD = 1024, D = 128;
  const int h = blockIdx.y, b = blockIdx.z;
  const int kvh = h >> 2;
  const int bk = b * 8 + kvh;
  const int tid = threadIdx.x;
  const int w = tid >> 6, l = tid & 63;
  const int l4 = l >> 4, l15 = l & 15;

  __shared__ alignas(16) __hip_bfloat16 Kt[2][64 * 128];
  __shared__ alignas(16) __hip_bfloat16 Vt[2][128 * 64];
  __shared__ alignas(16) __hip_bfloat16 Pb[4 * 32 * 64];

  const __hip_bfloat16* kSrc[4];
  const __hip_bfloat16* vSrc[4];
  int stDst[4];
  #pragma unroll
  for (int i = 0; i < 4; i++) {
    int c = i * 256 + tid;
    int kr = c >> 4;
    int kds = (c & 15) ^ (kr & 7);
    kSrc[i] = Kb + (size_t)(b * S + kr) * KVD + kvh * D + kds * 8;
    int vr = c >> 3;
    int vds = (c & 7) ^ (vr & 7);
    vSrc[i] = Vt_g + ((size_t)bk * 128 + vr) * 2048 + vds * 8;
    stDst[i] = (i * 256 + w * 64) * 16;
  }

  char* pbase = (char*)Pb + w * 4096;

  for (int pass = 0; pass < 2; pass++) {
    const int qt = pass ? (15 - blockIdx.x) : blockIdx.x;
    const int qbase = qt * 128 + w * 32;
    const int nt = 2 * qt + 2;

    bf16x8 qf[2][4];
    #pragma unroll
    for (int f = 0; f < 2; f++) {
      const int qrow = qbase + f * 16 + l15;
      const __hip_bfloat16* qptr = Q + (size_t)(b * S + qrow) * HD + h * D + l4 * 8;
      #pragma unroll
      for (int dc = 0; dc < 4; dc++) qf[f][dc] = *(const bf16x8*)(qptr + dc * 32);
    }

    f32x4 o[2][8];
    #pragma unroll
    for (int f = 0; f < 2; f++)
      #pragma unroll
      for (int nf = 0; nf < 8; nf++) o[f][nf] = (f32x4){0.f, 0.f, 0.f, 0.f};
    float mrun[2]  = {-1e30f, -1e30f};
    float llrun[2] = {0.f, 0.f};

    if (pass) __syncthreads();

    #pragma unroll
    for (int i = 0; i < 4; i++) {
      async_copy16(kSrc[i], (char*)Kt + stDst[i]);
      async_copy16(vSrc[i], (char*)Vt + stDst[i]);
    }

    int cur = 0;
    for (int t = 0; t < nt; t++) {
      __syncthreads();
      if (t + 1 < nt) {
        const int kv1 = (t + 1) * 64;
        #pragma unroll
        for (int i = 0; i < 4; i++) {
          async_copy16(kSrc[i] + (size_t)kv1 * KVD, (char*)Kt + (cur ^ 1) * 16384 + stDst[i]);
          async_copy16(vSrc[i] + kv1,               (char*)Vt + (cur ^ 1) * 16384 + stDst[i]);
        }
      }
      const char* ktb = (const char*)Kt + cur * 16384;
      const char* vtb = (const char*)Vt + cur * 16384;
      const int kv0 = t * 64;

      f32x4 s[2][4];
      #pragma unroll
      for (int f = 0; f < 2; f++)
        #pragma unroll
        for (int kg = 0; kg < 4; kg++) s[f][kg] = (f32x4){0.f, 0.f, 0.f, 0.f};
      __builtin_amdgcn_s_setprio(1);
      #pragma unroll
      for (int dc = 0; dc < 4; dc++) {
        #pragma unroll
        for (int kg = 0; kg < 4; kg++) {
          int key = kg * 16 + l15;
          int phys = (dc * 4 + l4) ^ (key & 7);
          bf16x8 kf = *(const bf16x8*)(ktb + key * 256 + phys * 16);
          s[0][kg] = __builtin_amdgcn_mfma_f32_16x16x32_bf16(kf, qf[0][dc], s[0][kg], 0, 0, 0);
          s[1][kg] = __builtin_amdgcn_mfma_f32_16x16x32_bf16(kf, qf[1][dc], s[1][kg], 0, 0, 0);
        }
      }
      __builtin_amdgcn_s_setprio(0);

      if (t >= nt - 2) {
        #pragma unroll
        for (int f = 0; f < 2; f++) {
          int q = qbase + f * 16 + l15;
          #pragma unroll
          for (int kg = 0; kg < 4; kg++)
            #pragma unroll
            for (int reg = 0; reg < 4; reg++)
              if (kv0 + kg * 16 + 4 * l4 + reg > q) s[f][kg][reg] = -1e30f;
        }
      }

      #pragma unroll
      for (int f = 0; f < 2; f++) {
        float pmax = -1e30f;
        #pragma unroll
        for (int kg = 0; kg < 4; kg++)
          #pragma unroll
          for (int reg = 0; reg < 4; reg++) pmax = fmaxf(pmax, s[f][kg][reg]);
        pmax = fmaxf(pmax, __shfl_xor(pmax, 16));
        pmax = fmaxf(pmax, __shfl_xor(pmax, 32));
        float mn = fmaxf(mrun[f], pmax);
        float alpha = __expf(mrun[f] - mn);
        mrun[f] = mn;
        float rs = 0.f;
        #pragma unroll
        for (int kg = 0; kg < 4; kg++)
          #pragma unroll
          for (int reg = 0; reg < 4; reg++) {
            float p = __expf(s[f][kg][reg] - mn);
            s[f][kg][reg] = p;
            rs += p;
          }
        rs += __shfl_xor(rs, 16);
        rs += __shfl_xor(rs, 32);
        llrun[f] = llrun[f] * alpha + rs;

        #pragma unroll
        for (int kg = 0; kg < 4; kg++)
          #pragma unroll
          for (int p2 = 0; p2 < 2; p2++) {
            unsigned u = pack_bf16x2(s[f][kg][2 * p2], s[f][kg][2 * p2 + 1]);
            int slot16 = 2 * kg + (l4 >> 1);
            int inner = (8 * l4 + 4 * p2) & 15;
            *(unsigned*)(pbase + (f * 16 + l15) * 128 + ((slot16 ^ (l15 & 7)) * 16) + inner) = u;
          }

        float alpha_r[4];
        #pragma unroll
        for (int reg = 0; reg < 4; reg++)
          alpha_r[reg] = __shfl(alpha, (l & 48) + 4 * l4 + reg);
        #pragma unroll
        for (int nf = 0; nf < 8; nf++)
          #pragma unroll
          for (int reg = 0; reg < 4; reg++) o[f][nf][reg] *= alpha_r[reg];
      }

      __builtin_amdgcn_s_setprio(1);
      #pragma unroll
      for (int half = 0; half < 2; half++) {
        int physp = (half * 4 + l4) ^ (l15 & 7);
        bf16x8 pa0 = *(const bf16x8*)(pbase + (0 * 16 + l15) * 128 + physp * 16);
        bf16x8 pa1 = *(const bf16x8*)(pbase + (1 * 16 + l15) * 128 + physp * 16);
        #pragma unroll
        for (int nf = 0; nf < 8; nf++) {
          int d = nf * 16 + l15;
          bf16x8 vf = *(const bf16x8*)(vtb + d * 128 + physp * 16);
          o[0][nf] = __builtin_amdgcn_mfma_f32_16x16x32_bf16(pa0, vf, o[0][nf], 0, 0, 0);
          o[1][nf] = __builtin_amdgcn_mfma_f32_16x16x32_bf16(pa1, vf, o[1][nf], 0, 0, 0);
        }
      }
      __builtin_amdgcn_s_setprio(0);
      cur ^= 1;
    }

    #pragma unroll
    for (int f = 0; f < 2; f++) {
      #pragma unroll
      for (int reg = 0; reg < 4; reg++) {
        float llr = __shfl(llrun[f], (l & 48) + 4 * l4 + reg);
        float inv = 1.0f / llr;
        int r = qbase + f * 16 + 4 * l4 + reg;
        __hip_bfloat16* optr = O + (size_t)(b * S + r) * HD + h * D + l15;
        #pragma unroll
        for (int nf = 0; nf < 8; nf++) optr[nf * 16] = __float2bfloat16(o[f][nf][reg] * inv);
      }
    }
  }
}

// ---------------------------------------------------------------------------
extern "C" void kernel_launch(void* const* d_in, const int* in_sizes, int n_in,
                              void* d_out, int out_size, void* d_ws, size_t ws_size,
                              hipStream_t stream) {
  const float* x    = (const float*)d_in[0];
  const float* fcos = (const float*)d_in[2];
  const float* fsin = (const float*)d_in[3];
  const float* wq   = (const float*)d_in[5];
  const float* wk   = (const float*)d_in[6];
  const float* wv   = (const float*)d_in[7];
  const float* wo   = (const float*)d_in[8];
  float* out = (float*)d_out;

  char* ws = (char*)d_ws;
  const size_t MB = 1024 * 1024;
  __hip_bfloat16* xb  = (__hip_bfloat16*)(ws + 0);        // 32MB; reused as ab
  __hip_bfloat16* wT  = (__hip_bfloat16*)(ws + 32 * MB);  // wqT; then vt; then woT
  __hip_bfloat16* wkT = (__hip_bfloat16*)(ws + 64 * MB);  // 8MB, contiguous with wvT
  __hip_bfloat16* wvT = (__hip_bfloat16*)(ws + 72 * MB);  // 8MB
  __hip_bfloat16* qb  = (__hip_bfloat16*)(ws + 80 * MB);
  __hip_bfloat16* kb  = (__hip_bfloat16*)(ws + 112 * MB);
  __hip_bfloat16* vb  = (__hip_bfloat16*)(ws + 120 * MB);
  __hip_bfloat16* ab  = xb;
  __hip_bfloat16* vt  = wT;

  const float qscale = 0.08838834764831845f;  // 1/sqrt(128)

  cvt_f32_bf16<<<16384, 256, 0, stream>>>(x, xb, 16777216);
  transpose_cvt<<<dim3(128, 128), dim3(32, 8), 0, stream>>>(wq, wT, 4096, 4096);
  transpose_cvt<<<dim3(32, 128), dim3(32, 8), 0, stream>>>(wk, wkT, 4096, 1024);
  transpose_cvt<<<dim3(32, 128), dim3(32, 8), 0, stream>>>(wv, wvT, 4096, 1024);

  // Q projection: 256 blocks = exactly one residency round (1 block/CU)
  gemm256<4><<<dim3(16, 16), 512, 0, stream>>>(xb, wT, nullptr, qb, nullptr, nullptr,
                                               4096, 4096, 4096, fcos, fsin, qscale);
  // fused K+V projection at 128^2 (512 blocks, 2/CU)
  gemm_bt<3><<<dim3(16, 32), 256, 0, stream>>>(xb, wkT, nullptr, kb, vb,
                                               4096, 2048, 4096, fcos, fsin, 1.0f);

  transpose_v<<<dim3(64, 4, 16), dim3(32, 8), 0, stream>>>(vb, vt);

  attn_kernel<<<dim3(8, 32, 2), 256, 0, stream>>>(qb, kb, vt, ab);

  transpose_cvt<<<dim3(128, 128), dim3(32, 8), 0, stream>>>(wo, wT, 4096, 4096);
  gemm256<0><<<dim3(16, 16), 512, 0, stream>>>(ab, wT, out, nullptr, nullptr, nullptr,
                                               4096, 4096, 4096, nullptr, nullptr, 1.0f);
}

// Round 16
// 506.579 us; speedup vs baseline: 1.1158x; 1.0584x over previous
//
#include <hip/hip_runtime.h>
#include <hip/hip_bf16.h>

typedef __bf16 bf16x8 __attribute__((ext_vector_type(8)));
typedef float  f32x4  __attribute__((ext_vector_type(4)));

#define DEVI __device__ __forceinline__

DEVI void async_copy16(const void* g, void* s) {
  __builtin_amdgcn_global_load_lds(
      (__attribute__((address_space(1))) void*)g,
      (__attribute__((address_space(3))) void*)s,
      16, 0, 0);
}

DEVI unsigned pack_bf16x2(float lo, float hi) {
  union { __hip_bfloat16 h[2]; unsigned u; } pk;
  pk.h[0] = __float2bfloat16(lo);
  pk.h[1] = __float2bfloat16(hi);
  return pk.u;
}

// ---------------------------------------------------------------------------
__global__ __launch_bounds__(256) void cvt_f32_bf16(const float* __restrict__ in,
                                                    __hip_bfloat16* __restrict__ out,
                                                    int n) {
  int i = (blockIdx.x * 256 + threadIdx.x) * 4;
  if (i >= n) return;
  float4 v = *(const float4*)(in + i);
  union { __hip_bfloat16 h[4]; ushort4 u; } o;
  o.h[0] = __float2bfloat16(v.x);
  o.h[1] = __float2bfloat16(v.y);
  o.h[2] = __float2bfloat16(v.z);
  o.h[3] = __float2bfloat16(v.w);
  *(ushort4*)(out + i) = o.u;
}

// ---------------------------------------------------------------------------
__global__ __launch_bounds__(256) void transpose_cvt(const float* __restrict__ W,
                                                     __hip_bfloat16* __restrict__ WT,
                                                     int Kdim, int Ndim) {
  __shared__ float tile[32][33];
  int bx = blockIdx.x * 32;
  int by = blockIdx.y * 32;
  int tx = threadIdx.x;
  int ty = threadIdx.y;
  #pragma unroll
  for (int j = 0; j < 32; j += 8)
    tile[ty + j][tx] = W[(size_t)(by + ty + j) * Ndim + bx + tx];
  __syncthreads();
  #pragma unroll
  for (int j = 0; j < 32; j += 8)
    WT[(size_t)(bx + ty + j) * Kdim + by + tx] = __float2bfloat16(tile[tx][ty + j]);
}

// ---------------------------------------------------------------------------
__global__ __launch_bounds__(256) void transpose_v(const __hip_bfloat16* __restrict__ vb,
                                                   __hip_bfloat16* __restrict__ vt) {
  __shared__ __hip_bfloat16 tile[32][33];
  const int s0 = blockIdx.x * 32, d0 = blockIdx.y * 32;
  const int bk = blockIdx.z;
  const int bb = bk >> 3, kvh = bk & 7;
  const int tx = threadIdx.x, ty = threadIdx.y;
  #pragma unroll
  for (int j = 0; j < 32; j += 8)
    tile[ty + j][tx] =
        vb[((size_t)(bb * 2048 + s0 + ty + j) * 8 + kvh) * 128 + d0 + tx];
  __syncthreads();
  #pragma unroll
  for (int j = 0; j < 32; j += 8)
    vt[((size_t)bk * 128 + d0 + ty + j) * 2048 + s0 + tx] = tile[tx][ty + j];
}

// ---------------------------------------------------------------------------
// 8-phase 256x256 GEMM — EXACT R12 template (EPI 0/2 only; R15 lesson:
// adding an EPI-4 instantiation regressed both instances 134->157 us,
// consistent with rule #19 codegen perturbation).
// Grid must be <= 256 blocks (128KB LDS -> 1 block/CU; R13/R14 lesson).
template <int EPI>
__global__ __launch_bounds__(512, 2) void gemm256(
    const __hip_bfloat16* __restrict__ A,
    const __hip_bfloat16* __restrict__ BT,
    float* __restrict__ Cf,
    __hip_bfloat16* __restrict__ Cb,
    int M, int N, int K,
    const float* __restrict__ fcos,
    const float* __restrict__ fsin,
    float scale) {
  __shared__ alignas(16) char lds[2][65536];
  const int tid = threadIdx.x;
  const int w = tid >> 6, l = tid & 63;
  const int l4 = l >> 4, l15 = l & 15;
  const int wr = w >> 2, wc = w & 3;      // 2M x 4N wave grid
  const int rowBase = blockIdx.y * 256;
  const int colBase = blockIdx.x * 256;

  const __hip_bfloat16* aS[2];
  const __hip_bfloat16* bS[2];
  int dstOff[2];
  #pragma unroll
  for (int i = 0; i < 2; i++) {
    int c = i * 512 + tid;
    int r = c >> 3;
    int kb = (c & 7) ^ (r & 7);
    aS[i] = A  + (size_t)(rowBase + r) * K + kb * 8;
    bS[i] = BT + (size_t)(colBase + r) * K + kb * 8;
    dstOff[i] = i * 8192 + w * 1024;     // wave-uniform; HW adds lane*16
  }
  const size_t hstep = (size_t)128 * K;  // +128 rows

  f32x4 acc[8][4];
  #pragma unroll
  for (int mi = 0; mi < 8; mi++)
    #pragma unroll
    for (int ni = 0; ni < 4; ni++)
      acc[mi][ni] = (f32x4){0.f, 0.f, 0.f, 0.f};

  // prologue: stage K-tile 0 -> buf0
  #pragma unroll
  for (int i = 0; i < 2; i++) async_copy16(aS[i],         lds[0] + 0     + dstOff[i]);
  #pragma unroll
  for (int i = 0; i < 2; i++) async_copy16(aS[i] + hstep, lds[0] + 16384 + dstOff[i]);
  #pragma unroll
  for (int i = 0; i < 2; i++) async_copy16(bS[i],         lds[0] + 32768 + dstOff[i]);
  #pragma unroll
  for (int i = 0; i < 2; i++) async_copy16(bS[i] + hstep, lds[0] + 49152 + dstOff[i]);

  const int NT = K >> 6;
  const int pswz = l15 & 7;              // read-side row-XOR component
  bf16x8 bF[4][2];

  for (int kt = 0; kt < NT; kt++) {
    const char* bufc = lds[kt & 1];
    char* bufn = lds[(kt & 1) ^ 1];
    const int koff = (kt + 1) * 64;
    const bool pre = (kt + 1 < NT);

    // ---------------- phase 0 ----------------
    if (pre) {
      #pragma unroll
      for (int i = 0; i < 2; i++) async_copy16(aS[i] + koff, bufn + 0 + dstOff[i]);
    }
    if (pre) { asm volatile("s_waitcnt vmcnt(2)" ::: "memory"); }
    else     { asm volatile("s_waitcnt vmcnt(0)" ::: "memory"); }
    __builtin_amdgcn_s_barrier();        // K-tile kt visible to all waves
    __builtin_amdgcn_sched_barrier(0);

    // all B frags (8 reads) + A frags mi=0,1 (4 reads)
    #pragma unroll
    for (int ni = 0; ni < 4; ni++)
      #pragma unroll
      for (int kh = 0; kh < 2; kh++) {
        int R = wc * 64 + ni * 16 + l15;
        int phys = (kh * 4 + l4) ^ pswz;
        bF[ni][kh] = *(const bf16x8*)(bufc + 32768 + (R >> 7) * 16384 +
                                      (R & 127) * 128 + phys * 16);
      }
    {
      bf16x8 aF[2][2];
      #pragma unroll
      for (int f = 0; f < 2; f++)
        #pragma unroll
        for (int kh = 0; kh < 2; kh++) {
          int lr = f * 16 + l15;
          int phys = (kh * 4 + l4) ^ pswz;
          aF[f][kh] = *(const bf16x8*)(bufc + wr * 16384 + lr * 128 + phys * 16);
        }
      asm volatile("s_waitcnt lgkmcnt(0)" ::: "memory");
      __builtin_amdgcn_sched_barrier(0);
      __builtin_amdgcn_s_setprio(1);
      #pragma unroll
      for (int f = 0; f < 2; f++)
        #pragma unroll
        for (int ni = 0; ni < 4; ni++)
          #pragma unroll
          for (int kh = 0; kh < 2; kh++)
            acc[f][ni] = __builtin_amdgcn_mfma_f32_16x16x32_bf16(
                aF[f][kh], bF[ni][kh], acc[f][ni], 0, 0, 0);
      __builtin_amdgcn_s_setprio(0);
    }
    __builtin_amdgcn_s_barrier();

    // ---------------- phases 1..3 ----------------
    #pragma unroll
    for (int p = 1; p < 4; p++) {
      bf16x8 aF[2][2];
      #pragma unroll
      for (int f = 0; f < 2; f++)
        #pragma unroll
        for (int kh = 0; kh < 2; kh++) {
          int lr = (2 * p + f) * 16 + l15;
          int phys = (kh * 4 + l4) ^ pswz;
          aF[f][kh] = *(const bf16x8*)(bufc + wr * 16384 + lr * 128 + phys * 16);
        }
      if (pre) {
        if (p == 1) {
          #pragma unroll
          for (int i = 0; i < 2; i++)
            async_copy16(aS[i] + hstep + koff, bufn + 16384 + dstOff[i]);
        } else if (p == 2) {
          #pragma unroll
          for (int i = 0; i < 2; i++)
            async_copy16(bS[i] + koff, bufn + 32768 + dstOff[i]);
        } else {
          #pragma unroll
          for (int i = 0; i < 2; i++)
            async_copy16(bS[i] + hstep + koff, bufn + 49152 + dstOff[i]);
        }
      }
      __builtin_amdgcn_s_barrier();
      asm volatile("s_waitcnt lgkmcnt(0)" ::: "memory");
      __builtin_amdgcn_sched_barrier(0);
      __builtin_amdgcn_s_setprio(1);
      #pragma unroll
      for (int f = 0; f < 2; f++)
        #pragma unroll
        for (int ni = 0; ni < 4; ni++)
          #pragma unroll
          for (int kh = 0; kh < 2; kh++)
            acc[2 * p + f][ni] = __builtin_amdgcn_mfma_f32_16x16x32_bf16(
                aF[f][kh], bF[ni][kh], acc[2 * p + f][ni], 0, 0, 0);
      __builtin_amdgcn_s_setprio(0);
      __builtin_amdgcn_s_barrier();
    }
  }

  // epilogue
  const int orow0 = rowBase + wr * 128 + l4 * 4;
  const int ocol0 = colBase + wc * 64 + l15;
  #pragma unroll
  for (int mi = 0; mi < 8; mi++) {
    #pragma unroll
    for (int ni = 0; ni < 4; ni++) {
      #pragma unroll
      for (int reg = 0; reg < 4; reg++) {
        int r = orow0 + mi * 16 + reg;
        int col = ocol0 + ni * 16;
        float v = acc[mi][ni][reg];
        if constexpr (EPI == 0) {
          Cf[(size_t)r * N + col] = v;
        } else {
          float p2 = __shfl_xor(v, 1);
          int dd = col & 127;
          int fi = dd >> 1;
          int srow = r & 2047;
          float c = fcos[srow * 64 + fi];
          float s = fsin[srow * 64 + fi];
          float outv = ((col & 1) == 0) ? (v * c - p2 * s) : (p2 * s + v * c);
          Cb[(size_t)r * N + col] = __float2bfloat16(outv * scale);
        }
      }
    }
  }
}

// ---------------------------------------------------------------------------
// 128x128 GEMM, 3-buffer 1-barrier pipeline (R11-verified) - fused KV proj.
// EPI 3: col<1024 -> RoPE -> Cb; col>=1024 -> Cb2 (both stride 1024)
template <int EPI>
__global__ __launch_bounds__(256) void gemm_bt(
    const __hip_bfloat16* __restrict__ A,
    const __hip_bfloat16* __restrict__ BT,
    float* __restrict__ Cf,
    __hip_bfloat16* __restrict__ Cb,
    __hip_bfloat16* __restrict__ Cb2,
    int M, int N, int K,
    const float* __restrict__ fcos,
    const float* __restrict__ fsin,
    float scale) {
  __shared__ alignas(16) __hip_bfloat16 lds[3][8192];
  const int tid = threadIdx.x;
  const int w = tid >> 6, l = tid & 63;
  const int l4 = l >> 4, l15 = l & 15;
  const int wr = w >> 1, wc = w & 1;
  const int rowBase = blockIdx.y * 128;
  const int colBase = blockIdx.x * 128;

  const __hip_bfloat16* aSrc[2];
  const __hip_bfloat16* bSrc[2];
  int dstOff[2];
  #pragma unroll
  for (int i = 0; i < 2; i++) {
    int c = i * 256 + tid;
    int r = c >> 2;
    int kb = (c & 3) ^ ((r >> 1) & 3);
    aSrc[i] = A  + (size_t)(rowBase + r) * K + kb * 8;
    bSrc[i] = BT + (size_t)(colBase + r) * K + kb * 8;
    dstOff[i] = (i * 256 + w * 64) * 16;
  }

  f32x4 acc[4][4];
  #pragma unroll
  for (int mi = 0; mi < 4; mi++)
    #pragma unroll
    for (int ni = 0; ni < 4; ni++)
      acc[mi][ni] = (f32x4){0.f, 0.f, 0.f, 0.f};

  #pragma unroll
  for (int i = 0; i < 2; i++) {
    async_copy16(aSrc[i], (char*)lds + dstOff[i]);
    async_copy16(bSrc[i], (char*)lds + 8192 + dstOff[i]);
  }
  #pragma unroll
  for (int i = 0; i < 2; i++) {
    async_copy16(aSrc[i] + 32, (char*)lds + 16384 + dstOff[i]);
    async_copy16(bSrc[i] + 32, (char*)lds + 16384 + 8192 + dstOff[i]);
  }

  int cur = 0;
  for (int k0 = 0; k0 < K; k0 += 32) {
    if (k0 + 32 < K) {
      asm volatile("s_waitcnt vmcnt(4)" ::: "memory");
    } else {
      asm volatile("s_waitcnt vmcnt(0)" ::: "memory");
    }
    __builtin_amdgcn_s_barrier();
    __builtin_amdgcn_sched_barrier(0);

    const char* base = (const char*)lds + cur * 16384;
    bf16x8 aF[4], bF[4];
    #pragma unroll
    for (int mi = 0; mi < 4; mi++) {
      int row = wr * 64 + mi * 16 + l15;
      int phys = l4 ^ ((row >> 1) & 3);
      aF[mi] = *(const bf16x8*)(base + row * 64 + phys * 16);
    }
    #pragma unroll
    for (int ni = 0; ni < 4; ni++) {
      int row = wc * 64 + ni * 16 + l15;
      int phys = l4 ^ ((row >> 1) & 3);
      bF[ni] = *(const bf16x8*)(base + 8192 + row * 64 + phys * 16);
    }
    asm volatile("s_waitcnt lgkmcnt(0)" ::: "memory");
    __builtin_amdgcn_sched_barrier(0);

    if (k0 + 64 < K) {
      int nxt = cur + 2; if (nxt >= 3) nxt -= 3;
      #pragma unroll
      for (int i = 0; i < 2; i++) {
        async_copy16(aSrc[i] + k0 + 64, (char*)lds + nxt * 16384 + dstOff[i]);
        async_copy16(bSrc[i] + k0 + 64, (char*)lds + nxt * 16384 + 8192 + dstOff[i]);
      }
    }

    __builtin_amdgcn_s_setprio(1);
    #pragma unroll
    for (int mi = 0; mi < 4; mi++)
      #pragma unroll
      for (int ni = 0; ni < 4; ni++)
        acc[mi][ni] = __builtin_amdgcn_mfma_f32_16x16x32_bf16(aF[mi], bF[ni], acc[mi][ni], 0, 0, 0);
    __builtin_amdgcn_s_setprio(0);
    cur = (cur + 1 == 3) ? 0 : cur + 1;
  }

  const int orow0 = rowBase + wr * 64 + l4 * 4;
  const int ocol0 = colBase + wc * 64 + l15;
  #pragma unroll
  for (int mi = 0; mi < 4; mi++) {
    #pragma unroll
    for (int ni = 0; ni < 4; ni++) {
      #pragma unroll
      for (int reg = 0; reg < 4; reg++) {
        int r = orow0 + mi * 16 + reg;
        int col = ocol0 + ni * 16;
        float v = acc[mi][ni][reg];
        if constexpr (EPI == 0) {
          Cf[(size_t)r * N + col] = v;
        } else if constexpr (EPI == 3) {
          if (colBase < 1024) {
            float p = __shfl_xor(v, 1);
            int fi = (col & 127) >> 1;
            int srow = r & 2047;
            float c = fcos[srow * 64 + fi];
            float s = fsin[srow * 64 + fi];
            float outv = ((col & 1) == 0) ? (v * c - p * s) : (p * s + v * c);
            Cb[(size_t)r * 1024 + col] = __float2bfloat16(outv);
          } else {
            Cb2[(size_t)r * 1024 + (col - 1024)] = __float2bfloat16(v);
          }
        }
      }
    }
  }
}

// ---------------------------------------------------------------------------
// flash attention v7: v6 + T13 defer-max (skip O-rescale when all rows'
// per-tile max growth <= 8; P bounded by e^8, fine in bf16/f32).
// qt-paired blocks, QBLK=128, KVBLK=64, swapped QK^T, in-lane softmax,
// 2-phase dbuf, setprio. grid (8, H, B).
__global__ __launch_bounds__(256, 2) void attn_kernel(
    const __hip_bfloat16* __restrict__ Q,
    const __hip_bfloat16* __restrict__ Kb,
    const __hip_bfloat16* __restrict__ Vt_g,
    __hip_bfloat16* __restrict__ O) {
  const int S = 2048, HD = 4096, KVD = 1024, D = 128;
  const int h = blockIdx.y, b = blockIdx.z;
  const int kvh = h >> 2;
  const int bk = b * 8 + kvh;
  const int tid = threadIdx.x;
  const int w = tid >> 6, l = tid & 63;
  const int l4 = l >> 4, l15 = l & 15;

  __shared__ alignas(16) __hip_bfloat16 Kt[2][64 * 128];
  __shared__ alignas(16) __hip_bfloat16 Vt[2][128 * 64];
  __shared__ alignas(16) __hip_bfloat16 Pb[4 * 32 * 64];

  const __hip_bfloat16* kSrc[4];
  const __hip_bfloat16* vSrc[4];
  int stDst[4];
  #pragma unroll
  for (int i = 0; i < 4; i++) {
    int c = i * 256 + tid;
    int kr = c >> 4;
    int kds = (c & 15) ^ (kr & 7);
    kSrc[i] = Kb + (size_t)(b * S + kr) * KVD + kvh * D + kds * 8;
    int vr = c >> 3;
    int vds = (c & 7) ^ (vr & 7);
    vSrc[i] = Vt_g + ((size_t)bk * 128 + vr) * 2048 + vds * 8;
    stDst[i] = (i * 256 + w * 64) * 16;
  }

  char* pbase = (char*)Pb + w * 4096;

  for (int pass = 0; pass < 2; pass++) {
    const int qt = pass ? (15 - blockIdx.x) : blockIdx.x;
    const int qbase = qt * 128 + w * 32;
    const int nt = 2 * qt + 2;

    bf16x8 qf[2][4];
    #pragma unroll
    for (int f = 0; f < 2; f++) {
      const int qrow = qbase + f * 16 + l15;
      const __hip_bfloat16* qptr = Q + (size_t)(b * S + qrow) * HD + h * D + l4 * 8;
      #pragma unroll
      for (int dc = 0; dc < 4; dc++) qf[f][dc] = *(const bf16x8*)(qptr + dc * 32);
    }

    f32x4 o[2][8];
    #pragma unroll
    for (int f = 0; f < 2; f++)
      #pragma unroll
      for (int nf = 0; nf < 8; nf++) o[f][nf] = (f32x4){0.f, 0.f, 0.f, 0.f};
    float mrun[2]  = {-1e30f, -1e30f};
    float llrun[2] = {0.f, 0.f};

    if (pass) __syncthreads();

    #pragma unroll
    for (int i = 0; i < 4; i++) {
      async_copy16(kSrc[i], (char*)Kt + stDst[i]);
      async_copy16(vSrc[i], (char*)Vt + stDst[i]);
    }

    int cur = 0;
    for (int t = 0; t < nt; t++) {
      __syncthreads();
      if (t + 1 < nt) {
        const int kv1 = (t + 1) * 64;
        #pragma unroll
        for (int i = 0; i < 4; i++) {
          async_copy16(kSrc[i] + (size_t)kv1 * KVD, (char*)Kt + (cur ^ 1) * 16384 + stDst[i]);
          async_copy16(vSrc[i] + kv1,               (char*)Vt + (cur ^ 1) * 16384 + stDst[i]);
        }
      }
      const char* ktb = (const char*)Kt + cur * 16384;
      const char* vtb = (const char*)Vt + cur * 16384;
      const int kv0 = t * 64;

      f32x4 s[2][4];
      #pragma unroll
      for (int f = 0; f < 2; f++)
        #pragma unroll
        for (int kg = 0; kg < 4; kg++) s[f][kg] = (f32x4){0.f, 0.f, 0.f, 0.f};
      __builtin_amdgcn_s_setprio(1);
      #pragma unroll
      for (int dc = 0; dc < 4; dc++) {
        #pragma unroll
        for (int kg = 0; kg < 4; kg++) {
          int key = kg * 16 + l15;
          int phys = (dc * 4 + l4) ^ (key & 7);
          bf16x8 kf = *(const bf16x8*)(ktb + key * 256 + phys * 16);
          s[0][kg] = __builtin_amdgcn_mfma_f32_16x16x32_bf16(kf, qf[0][dc], s[0][kg], 0, 0, 0);
          s[1][kg] = __builtin_amdgcn_mfma_f32_16x16x32_bf16(kf, qf[1][dc], s[1][kg], 0, 0, 0);
        }
      }
      __builtin_amdgcn_s_setprio(0);

      if (t >= nt - 2) {
        #pragma unroll
        for (int f = 0; f < 2; f++) {
          int q = qbase + f * 16 + l15;
          #pragma unroll
          for (int kg = 0; kg < 4; kg++)
            #pragma unroll
            for (int reg = 0; reg < 4; reg++)
              if (kv0 + kg * 16 + 4 * l4 + reg > q) s[f][kg][reg] = -1e30f;
        }
      }

      #pragma unroll
      for (int f = 0; f < 2; f++) {
        float pmax = -1e30f;
        #pragma unroll
        for (int kg = 0; kg < 4; kg++)
          #pragma unroll
          for (int reg = 0; reg < 4; reg++) pmax = fmaxf(pmax, s[f][kg][reg]);
        pmax = fmaxf(pmax, __shfl_xor(pmax, 16));
        pmax = fmaxf(pmax, __shfl_xor(pmax, 32));

        // T13 defer-max: rescale only if some row grew > THR=8
        float mn;
        if (__any(pmax > mrun[f] + 8.0f)) {
          mn = fmaxf(mrun[f], pmax);
          float alpha = __expf(mrun[f] - mn);
          mrun[f] = mn;
          llrun[f] *= alpha;
          float alpha_r[4];
          #pragma unroll
          for (int reg = 0; reg < 4; reg++)
            alpha_r[reg] = __shfl(alpha, (l & 48) + 4 * l4 + reg);
          #pragma unroll
          for (int nf = 0; nf < 8; nf++)
            #pragma unroll
            for (int reg = 0; reg < 4; reg++) o[f][nf][reg] *= alpha_r[reg];
        } else {
          mn = mrun[f];
        }

        float rs = 0.f;
        #pragma unroll
        for (int kg = 0; kg < 4; kg++)
          #pragma unroll
          for (int reg = 0; reg < 4; reg++) {
            float p = __expf(s[f][kg][reg] - mn);
            s[f][kg][reg] = p;
            rs += p;
          }
        rs += __shfl_xor(rs, 16);
        rs += __shfl_xor(rs, 32);
        llrun[f] += rs;

        #pragma unroll
        for (int kg = 0; kg < 4; kg++)
          #pragma unroll
          for (int p2 = 0; p2 < 2; p2++) {
            unsigned u = pack_bf16x2(s[f][kg][2 * p2], s[f][kg][2 * p2 + 1]);
            int slot16 = 2 * kg + (l4 >> 1);
            int inner = (8 * l4 + 4 * p2) & 15;
            *(unsigned*)(pbase + (f * 16 + l15) * 128 + ((slot16 ^ (l15 & 7)) * 16) + inner) = u;
          }
      }

      __builtin_amdgcn_s_setprio(1);
      #pragma unroll
      for (int half = 0; half < 2; half++) {
        int physp = (half * 4 + l4) ^ (l15 & 7);
        bf16x8 pa0 = *(const bf16x8*)(pbase + (0 * 16 + l15) * 128 + physp * 16);
        bf16x8 pa1 = *(const bf16x8*)(pbase + (1 * 16 + l15) * 128 + physp * 16);
        #pragma unroll
        for (int nf = 0; nf < 8; nf++) {
          int d = nf * 16 + l15;
          bf16x8 vf = *(const bf16x8*)(vtb + d * 128 + physp * 16);
          o[0][nf] = __builtin_amdgcn_mfma_f32_16x16x32_bf16(pa0, vf, o[0][nf], 0, 0, 0);
          o[1][nf] = __builtin_amdgcn_mfma_f32_16x16x32_bf16(pa1, vf, o[1][nf], 0, 0, 0);
        }
      }
      __builtin_amdgcn_s_setprio(0);
      cur ^= 1;
    }

    #pragma unroll
    for (int f = 0; f < 2; f++) {
      #pragma unroll
      for (int reg = 0; reg < 4; reg++) {
        float llr = __shfl(llrun[f], (l & 48) + 4 * l4 + reg);
        float inv = 1.0f / llr;
        int r = qbase + f * 16 + 4 * l4 + reg;
        __hip_bfloat16* optr = O + (size_t)(b * S + r) * HD + h * D + l15;
        #pragma unroll
        for (int nf = 0; nf < 8; nf++) optr[nf * 16] = __float2bfloat16(o[f][nf][reg] * inv);
      }
    }
  }
}

// ---------------------------------------------------------------------------
extern "C" void kernel_launch(void* const* d_in, const int* in_sizes, int n_in,
                              void* d_out, int out_size, void* d_ws, size_t ws_size,
                              hipStream_t stream) {
  const float* x    = (const float*)d_in[0];
  const float* fcos = (const float*)d_in[2];
  const float* fsin = (const float*)d_in[3];
  const float* wq   = (const float*)d_in[5];
  const float* wk   = (const float*)d_in[6];
  const float* wv   = (const float*)d_in[7];
  const float* wo   = (const float*)d_in[8];
  float* out = (float*)d_out;

  char* ws = (char*)d_ws;
  const size_t MB = 1024 * 1024;
  __hip_bfloat16* xb  = (__hip_bfloat16*)(ws + 0);        // 32MB; reused as ab
  __hip_bfloat16* wT  = (__hip_bfloat16*)(ws + 32 * MB);  // wqT; then vt; then woT
  __hip_bfloat16* wkT = (__hip_bfloat16*)(ws + 64 * MB);  // 8MB, contiguous with wvT
  __hip_bfloat16* wvT = (__hip_bfloat16*)(ws + 72 * MB);  // 8MB
  __hip_bfloat16* qb  = (__hip_bfloat16*)(ws + 80 * MB);
  __hip_bfloat16* kb  = (__hip_bfloat16*)(ws + 112 * MB);
  __hip_bfloat16* vb  = (__hip_bfloat16*)(ws + 120 * MB);
  __hip_bfloat16* ab  = xb;
  __hip_bfloat16* vt  = wT;

  const float qscale = 0.08838834764831845f;  // 1/sqrt(128)

  cvt_f32_bf16<<<16384, 256, 0, stream>>>(x, xb, 16777216);
  transpose_cvt<<<dim3(128, 128), dim3(32, 8), 0, stream>>>(wq, wT, 4096, 4096);
  transpose_cvt<<<dim3(32, 128), dim3(32, 8), 0, stream>>>(wk, wkT, 4096, 1024);
  transpose_cvt<<<dim3(32, 128), dim3(32, 8), 0, stream>>>(wv, wvT, 4096, 1024);

  gemm256<2><<<dim3(16, 16), 512, 0, stream>>>(xb, wT, nullptr, qb,
                                               4096, 4096, 4096, fcos, fsin, qscale);
  // fused K+V projection: BT = [wkT ; wvT] (contiguous), N=2048
  gemm_bt<3><<<dim3(16, 32), 256, 0, stream>>>(xb, wkT, nullptr, kb, vb,
                                               4096, 2048, 4096, fcos, fsin, 1.0f);

  transpose_v<<<dim3(64, 4, 16), dim3(32, 8), 0, stream>>>(vb, vt);

  attn_kernel<<<dim3(8, 32, 2), 256, 0, stream>>>(qb, kb, vt, ab);

  transpose_cvt<<<dim3(128, 128), dim3(32, 8), 0, stream>>>(wo, wT, 4096, 4096);
  gemm256<0><<<dim3(16, 16), 512, 0, stream>>>(ab, wT, out, nullptr,
                                               4096, 4096, 4096, nullptr, nullptr, 1.0f);
}

// Round 17
// 506.227 us; speedup vs baseline: 1.1166x; 1.0007x over previous
//
#include <hip/hip_runtime.h>
#include <hip/hip_bf16.h>

typedef __bf16 bf16x8 __attribute__((ext_vector_type(8)));
typedef float  f32x4  __attribute__((ext_vector_type(4)));

#define DEVI __device__ __forceinline__

DEVI void async_copy16(const void* g, void* s) {
  __builtin_amdgcn_global_load_lds(
      (__attribute__((address_space(1))) void*)g,
      (__attribute__((address_space(3))) void*)s,
      16, 0, 0);
}

DEVI unsigned pack_bf16x2(float lo, float hi) {
  union { __hip_bfloat16 h[2]; unsigned u; } pk;
  pk.h[0] = __float2bfloat16(lo);
  pk.h[1] = __float2bfloat16(hi);
  return pk.u;
}

// ---------------------------------------------------------------------------
__global__ __launch_bounds__(256) void cvt_f32_bf16(const float* __restrict__ in,
                                                    __hip_bfloat16* __restrict__ out,
                                                    int n) {
  int i = (blockIdx.x * 256 + threadIdx.x) * 4;
  if (i >= n) return;
  float4 v = *(const float4*)(in + i);
  union { __hip_bfloat16 h[4]; ushort4 u; } o;
  o.h[0] = __float2bfloat16(v.x);
  o.h[1] = __float2bfloat16(v.y);
  o.h[2] = __float2bfloat16(v.z);
  o.h[3] = __float2bfloat16(v.w);
  *(ushort4*)(out + i) = o.u;
}

// ---------------------------------------------------------------------------
__global__ __launch_bounds__(256) void transpose_cvt(const float* __restrict__ W,
                                                     __hip_bfloat16* __restrict__ WT,
                                                     int Kdim, int Ndim) {
  __shared__ float tile[32][33];
  int bx = blockIdx.x * 32;
  int by = blockIdx.y * 32;
  int tx = threadIdx.x;
  int ty = threadIdx.y;
  #pragma unroll
  for (int j = 0; j < 32; j += 8)
    tile[ty + j][tx] = W[(size_t)(by + ty + j) * Ndim + bx + tx];
  __syncthreads();
  #pragma unroll
  for (int j = 0; j < 32; j += 8)
    WT[(size_t)(bx + ty + j) * Kdim + by + tx] = __float2bfloat16(tile[tx][ty + j]);
}

// ---------------------------------------------------------------------------
__global__ __launch_bounds__(256) void transpose_v(const __hip_bfloat16* __restrict__ vb,
                                                   __hip_bfloat16* __restrict__ vt) {
  __shared__ __hip_bfloat16 tile[32][33];
  const int s0 = blockIdx.x * 32, d0 = blockIdx.y * 32;
  const int bk = blockIdx.z;
  const int bb = bk >> 3, kvh = bk & 7;
  const int tx = threadIdx.x, ty = threadIdx.y;
  #pragma unroll
  for (int j = 0; j < 32; j += 8)
    tile[ty + j][tx] =
        vb[((size_t)(bb * 2048 + s0 + ty + j) * 8 + kvh) * 128 + d0 + tx];
  __syncthreads();
  #pragma unroll
  for (int j = 0; j < 32; j += 8)
    vt[((size_t)bk * 128 + d0 + ty + j) * 2048 + s0 + tx] = tile[tx][ty + j];
}

// ---------------------------------------------------------------------------
// 8-phase 256x256 GEMM — R16 template + COUNTED lgkm waits (m201 pattern):
// each phase's MFMA cluster split by k-half; first half starts after
// lgkmcnt(N) while second-batch reads land. Barriers/vmcnt/staging order
// bit-identical to the verified R16 schedule.
// Grid must be <= 256 blocks (128KB LDS -> 1 block/CU).
// EPI 0: f32 -> Cf;  EPI 2: bf16 RoPE*scale -> Cb (stride N).
template <int EPI>
__global__ __launch_bounds__(512, 2) void gemm256(
    const __hip_bfloat16* __restrict__ A,
    const __hip_bfloat16* __restrict__ BT,
    float* __restrict__ Cf,
    __hip_bfloat16* __restrict__ Cb,
    int M, int N, int K,
    const float* __restrict__ fcos,
    const float* __restrict__ fsin,
    float scale) {
  __shared__ alignas(16) char lds[2][65536];
  const int tid = threadIdx.x;
  const int w = tid >> 6, l = tid & 63;
  const int l4 = l >> 4, l15 = l & 15;
  const int wr = w >> 2, wc = w & 3;      // 2M x 4N wave grid
  const int rowBase = blockIdx.y * 256;
  const int colBase = blockIdx.x * 256;

  const __hip_bfloat16* aS[2];
  const __hip_bfloat16* bS[2];
  int dstOff[2];
  #pragma unroll
  for (int i = 0; i < 2; i++) {
    int c = i * 512 + tid;
    int r = c >> 3;
    int kb = (c & 7) ^ (r & 7);
    aS[i] = A  + (size_t)(rowBase + r) * K + kb * 8;
    bS[i] = BT + (size_t)(colBase + r) * K + kb * 8;
    dstOff[i] = i * 8192 + w * 1024;     // wave-uniform; HW adds lane*16
  }
  const size_t hstep = (size_t)128 * K;  // +128 rows

  f32x4 acc[8][4];
  #pragma unroll
  for (int mi = 0; mi < 8; mi++)
    #pragma unroll
    for (int ni = 0; ni < 4; ni++)
      acc[mi][ni] = (f32x4){0.f, 0.f, 0.f, 0.f};

  // prologue: stage K-tile 0 -> buf0
  #pragma unroll
  for (int i = 0; i < 2; i++) async_copy16(aS[i],         lds[0] + 0     + dstOff[i]);
  #pragma unroll
  for (int i = 0; i < 2; i++) async_copy16(aS[i] + hstep, lds[0] + 16384 + dstOff[i]);
  #pragma unroll
  for (int i = 0; i < 2; i++) async_copy16(bS[i],         lds[0] + 32768 + dstOff[i]);
  #pragma unroll
  for (int i = 0; i < 2; i++) async_copy16(bS[i] + hstep, lds[0] + 49152 + dstOff[i]);

  const int NT = K >> 6;
  const int pswz = l15 & 7;              // read-side row-XOR component
  bf16x8 bF[4][2];

  for (int kt = 0; kt < NT; kt++) {
    const char* bufc = lds[kt & 1];
    char* bufn = lds[(kt & 1) ^ 1];
    const int koff = (kt + 1) * 64;
    const bool pre = (kt + 1 < NT);

    // ---------------- phase 0 ----------------
    if (pre) {
      #pragma unroll
      for (int i = 0; i < 2; i++) async_copy16(aS[i] + koff, bufn + 0 + dstOff[i]);
    }
    if (pre) { asm volatile("s_waitcnt vmcnt(2)" ::: "memory"); }
    else     { asm volatile("s_waitcnt vmcnt(0)" ::: "memory"); }
    __builtin_amdgcn_s_barrier();        // K-tile kt visible to all waves
    __builtin_amdgcn_sched_barrier(0);

    {
      bf16x8 aF[2][2];
      // batch 1: B kh=0 (4 reads) + A p0 kh=0 (2 reads)
      #pragma unroll
      for (int ni = 0; ni < 4; ni++) {
        int R = wc * 64 + ni * 16 + l15;
        int phys = (0 * 4 + l4) ^ pswz;
        bF[ni][0] = *(const bf16x8*)(bufc + 32768 + (R >> 7) * 16384 +
                                     (R & 127) * 128 + phys * 16);
      }
      #pragma unroll
      for (int f = 0; f < 2; f++) {
        int lr = f * 16 + l15;
        int phys = (0 * 4 + l4) ^ pswz;
        aF[f][0] = *(const bf16x8*)(bufc + wr * 16384 + lr * 128 + phys * 16);
      }
      __builtin_amdgcn_sched_barrier(0);
      // batch 2: B kh=1 (4 reads) + A p0 kh=1 (2 reads)
      #pragma unroll
      for (int ni = 0; ni < 4; ni++) {
        int R = wc * 64 + ni * 16 + l15;
        int phys = (1 * 4 + l4) ^ pswz;
        bF[ni][1] = *(const bf16x8*)(bufc + 32768 + (R >> 7) * 16384 +
                                     (R & 127) * 128 + phys * 16);
      }
      #pragma unroll
      for (int f = 0; f < 2; f++) {
        int lr = f * 16 + l15;
        int phys = (1 * 4 + l4) ^ pswz;
        aF[f][1] = *(const bf16x8*)(bufc + wr * 16384 + lr * 128 + phys * 16);
      }
      __builtin_amdgcn_sched_barrier(0);
      asm volatile("s_waitcnt lgkmcnt(6)" ::: "memory");  // batch 1 complete
      __builtin_amdgcn_sched_barrier(0);
      __builtin_amdgcn_s_setprio(1);
      #pragma unroll
      for (int f = 0; f < 2; f++)
        #pragma unroll
        for (int ni = 0; ni < 4; ni++)
          acc[f][ni] = __builtin_amdgcn_mfma_f32_16x16x32_bf16(
              aF[f][0], bF[ni][0], acc[f][ni], 0, 0, 0);
      __builtin_amdgcn_s_setprio(0);
      asm volatile("s_waitcnt lgkmcnt(0)" ::: "memory");  // batch 2 complete
      __builtin_amdgcn_sched_barrier(0);
      __builtin_amdgcn_s_setprio(1);
      #pragma unroll
      for (int f = 0; f < 2; f++)
        #pragma unroll
        for (int ni = 0; ni < 4; ni++)
          acc[f][ni] = __builtin_amdgcn_mfma_f32_16x16x32_bf16(
              aF[f][1], bF[ni][1], acc[f][ni], 0, 0, 0);
      __builtin_amdgcn_s_setprio(0);
    }
    __builtin_amdgcn_s_barrier();

    // ---------------- phases 1..3 ----------------
    #pragma unroll
    for (int p = 1; p < 4; p++) {
      bf16x8 aF[2][2];
      // kh=0 reads first (order pinned), then kh=1
      #pragma unroll
      for (int f = 0; f < 2; f++) {
        int lr = (2 * p + f) * 16 + l15;
        int phys = (0 * 4 + l4) ^ pswz;
        aF[f][0] = *(const bf16x8*)(bufc + wr * 16384 + lr * 128 + phys * 16);
      }
      __builtin_amdgcn_sched_barrier(0);
      #pragma unroll
      for (int f = 0; f < 2; f++) {
        int lr = (2 * p + f) * 16 + l15;
        int phys = (1 * 4 + l4) ^ pswz;
        aF[f][1] = *(const bf16x8*)(bufc + wr * 16384 + lr * 128 + phys * 16);
      }
      __builtin_amdgcn_sched_barrier(0);
      if (pre) {
        if (p == 1) {
          #pragma unroll
          for (int i = 0; i < 2; i++)
            async_copy16(aS[i] + hstep + koff, bufn + 16384 + dstOff[i]);
        } else if (p == 2) {
          #pragma unroll
          for (int i = 0; i < 2; i++)
            async_copy16(bS[i] + koff, bufn + 32768 + dstOff[i]);
        } else {
          #pragma unroll
          for (int i = 0; i < 2; i++)
            async_copy16(bS[i] + hstep + koff, bufn + 49152 + dstOff[i]);
        }
      }
      __builtin_amdgcn_s_barrier();
      asm volatile("s_waitcnt lgkmcnt(2)" ::: "memory");  // kh=0 reads done
      __builtin_amdgcn_sched_barrier(0);
      __builtin_amdgcn_s_setprio(1);
      #pragma unroll
      for (int f = 0; f < 2; f++)
        #pragma unroll
        for (int ni = 0; ni < 4; ni++)
          acc[2 * p + f][ni] = __builtin_amdgcn_mfma_f32_16x16x32_bf16(
              aF[f][0], bF[ni][0], acc[2 * p + f][ni], 0, 0, 0);
      __builtin_amdgcn_s_setprio(0);
      asm volatile("s_waitcnt lgkmcnt(0)" ::: "memory");  // kh=1 reads done
      __builtin_amdgcn_sched_barrier(0);
      __builtin_amdgcn_s_setprio(1);
      #pragma unroll
      for (int f = 0; f < 2; f++)
        #pragma unroll
        for (int ni = 0; ni < 4; ni++)
          acc[2 * p + f][ni] = __builtin_amdgcn_mfma_f32_16x16x32_bf16(
              aF[f][1], bF[ni][1], acc[2 * p + f][ni], 0, 0, 0);
      __builtin_amdgcn_s_setprio(0);
      __builtin_amdgcn_s_barrier();
    }
  }

  // epilogue
  const int orow0 = rowBase + wr * 128 + l4 * 4;
  const int ocol0 = colBase + wc * 64 + l15;
  #pragma unroll
  for (int mi = 0; mi < 8; mi++) {
    #pragma unroll
    for (int ni = 0; ni < 4; ni++) {
      #pragma unroll
      for (int reg = 0; reg < 4; reg++) {
        int r = orow0 + mi * 16 + reg;
        int col = ocol0 + ni * 16;
        float v = acc[mi][ni][reg];
        if constexpr (EPI == 0) {
          Cf[(size_t)r * N + col] = v;
        } else {
          float p2 = __shfl_xor(v, 1);
          int dd = col & 127;
          int fi = dd >> 1;
          int srow = r & 2047;
          float c = fcos[srow * 64 + fi];
          float s = fsin[srow * 64 + fi];
          float outv = ((col & 1) == 0) ? (v * c - p2 * s) : (p2 * s + v * c);
          Cb[(size_t)r * N + col] = __float2bfloat16(outv * scale);
        }
      }
    }
  }
}

// ---------------------------------------------------------------------------
// 128x128 GEMM, 3-buffer 1-barrier pipeline (R11-verified) - fused KV proj.
// EPI 3: col<1024 -> RoPE -> Cb; col>=1024 -> Cb2 (both stride 1024)
template <int EPI>
__global__ __launch_bounds__(256) void gemm_bt(
    const __hip_bfloat16* __restrict__ A,
    const __hip_bfloat16* __restrict__ BT,
    float* __restrict__ Cf,
    __hip_bfloat16* __restrict__ Cb,
    __hip_bfloat16* __restrict__ Cb2,
    int M, int N, int K,
    const float* __restrict__ fcos,
    const float* __restrict__ fsin,
    float scale) {
  __shared__ alignas(16) __hip_bfloat16 lds[3][8192];
  const int tid = threadIdx.x;
  const int w = tid >> 6, l = tid & 63;
  const int l4 = l >> 4, l15 = l & 15;
  const int wr = w >> 1, wc = w & 1;
  const int rowBase = blockIdx.y * 128;
  const int colBase = blockIdx.x * 128;

  const __hip_bfloat16* aSrc[2];
  const __hip_bfloat16* bSrc[2];
  int dstOff[2];
  #pragma unroll
  for (int i = 0; i < 2; i++) {
    int c = i * 256 + tid;
    int r = c >> 2;
    int kb = (c & 3) ^ ((r >> 1) & 3);
    aSrc[i] = A  + (size_t)(rowBase + r) * K + kb * 8;
    bSrc[i] = BT + (size_t)(colBase + r) * K + kb * 8;
    dstOff[i] = (i * 256 + w * 64) * 16;
  }

  f32x4 acc[4][4];
  #pragma unroll
  for (int mi = 0; mi < 4; mi++)
    #pragma unroll
    for (int ni = 0; ni < 4; ni++)
      acc[mi][ni] = (f32x4){0.f, 0.f, 0.f, 0.f};

  #pragma unroll
  for (int i = 0; i < 2; i++) {
    async_copy16(aSrc[i], (char*)lds + dstOff[i]);
    async_copy16(bSrc[i], (char*)lds + 8192 + dstOff[i]);
  }
  #pragma unroll
  for (int i = 0; i < 2; i++) {
    async_copy16(aSrc[i] + 32, (char*)lds + 16384 + dstOff[i]);
    async_copy16(bSrc[i] + 32, (char*)lds + 16384 + 8192 + dstOff[i]);
  }

  int cur = 0;
  for (int k0 = 0; k0 < K; k0 += 32) {
    if (k0 + 32 < K) {
      asm volatile("s_waitcnt vmcnt(4)" ::: "memory");
    } else {
      asm volatile("s_waitcnt vmcnt(0)" ::: "memory");
    }
    __builtin_amdgcn_s_barrier();
    __builtin_amdgcn_sched_barrier(0);

    const char* base = (const char*)lds + cur * 16384;
    bf16x8 aF[4], bF[4];
    #pragma unroll
    for (int mi = 0; mi < 4; mi++) {
      int row = wr * 64 + mi * 16 + l15;
      int phys = l4 ^ ((row >> 1) & 3);
      aF[mi] = *(const bf16x8*)(base + row * 64 + phys * 16);
    }
    #pragma unroll
    for (int ni = 0; ni < 4; ni++) {
      int row = wc * 64 + ni * 16 + l15;
      int phys = l4 ^ ((row >> 1) & 3);
      bF[ni] = *(const bf16x8*)(base + 8192 + row * 64 + phys * 16);
    }
    asm volatile("s_waitcnt lgkmcnt(0)" ::: "memory");
    __builtin_amdgcn_sched_barrier(0);

    if (k0 + 64 < K) {
      int nxt = cur + 2; if (nxt >= 3) nxt -= 3;
      #pragma unroll
      for (int i = 0; i < 2; i++) {
        async_copy16(aSrc[i] + k0 + 64, (char*)lds + nxt * 16384 + dstOff[i]);
        async_copy16(bSrc[i] + k0 + 64, (char*)lds + nxt * 16384 + 8192 + dstOff[i]);
      }
    }

    __builtin_amdgcn_s_setprio(1);
    #pragma unroll
    for (int mi = 0; mi < 4; mi++)
      #pragma unroll
      for (int ni = 0; ni < 4; ni++)
        acc[mi][ni] = __builtin_amdgcn_mfma_f32_16x16x32_bf16(aF[mi], bF[ni], acc[mi][ni], 0, 0, 0);
    __builtin_amdgcn_s_setprio(0);
    cur = (cur + 1 == 3) ? 0 : cur + 1;
  }

  const int orow0 = rowBase + wr * 64 + l4 * 4;
  const int ocol0 = colBase + wc * 64 + l15;
  #pragma unroll
  for (int mi = 0; mi < 4; mi++) {
    #pragma unroll
    for (int ni = 0; ni < 4; ni++) {
      #pragma unroll
      for (int reg = 0; reg < 4; reg++) {
        int r = orow0 + mi * 16 + reg;
        int col = ocol0 + ni * 16;
        float v = acc[mi][ni][reg];
        if constexpr (EPI == 0) {
          Cf[(size_t)r * N + col] = v;
        } else if constexpr (EPI == 3) {
          if (colBase < 1024) {
            float p = __shfl_xor(v, 1);
            int fi = (col & 127) >> 1;
            int srow = r & 2047;
            float c = fcos[srow * 64 + fi];
            float s = fsin[srow * 64 + fi];
            float outv = ((col & 1) == 0) ? (v * c - p * s) : (p * s + v * c);
            Cb[(size_t)r * 1024 + col] = __float2bfloat16(outv);
          } else {
            Cb2[(size_t)r * 1024 + (col - 1024)] = __float2bfloat16(v);
          }
        }
      }
    }
  }
}

// ---------------------------------------------------------------------------
// flash attention v7 (R16-verified): qt-paired blocks, QBLK=128, KVBLK=64,
// swapped QK^T, in-lane softmax, T13 defer-max, 2-phase dbuf, setprio.
__global__ __launch_bounds__(256, 2) void attn_kernel(
    const __hip_bfloat16* __restrict__ Q,
    const __hip_bfloat16* __restrict__ Kb,
    const __hip_bfloat16* __restrict__ Vt_g,
    __hip_bfloat16* __restrict__ O) {
  const int S = 2048, HD = 4096, KVD = 1024, D = 128;
  const int h = blockIdx.y, b = blockIdx.z;
  const int kvh = h >> 2;
  const int bk = b * 8 + kvh;
  const int tid = threadIdx.x;
  const int w = tid >> 6, l = tid & 63;
  const int l4 = l >> 4, l15 = l & 15;

  __shared__ alignas(16) __hip_bfloat16 Kt[2][64 * 128];
  __shared__ alignas(16) __hip_bfloat16 Vt[2][128 * 64];
  __shared__ alignas(16) __hip_bfloat16 Pb[4 * 32 * 64];

  const __hip_bfloat16* kSrc[4];
  const __hip_bfloat16* vSrc[4];
  int stDst[4];
  #pragma unroll
  for (int i = 0; i < 4; i++) {
    int c = i * 256 + tid;
    int kr = c >> 4;
    int kds = (c & 15) ^ (kr & 7);
    kSrc[i] = Kb + (size_t)(b * S + kr) * KVD + kvh * D + kds * 8;
    int vr = c >> 3;
    int vds = (c & 7) ^ (vr & 7);
    vSrc[i] = Vt_g + ((size_t)bk * 128 + vr) * 2048 + vds * 8;
    stDst[i] = (i * 256 + w * 64) * 16;
  }

  char* pbase = (char*)Pb + w * 4096;

  for (int pass = 0; pass < 2; pass++) {
    const int qt = pass ? (15 - blockIdx.x) : blockIdx.x;
    const int qbase = qt * 128 + w * 32;
    const int nt = 2 * qt + 2;

    bf16x8 qf[2][4];
    #pragma unroll
    for (int f = 0; f < 2; f++) {
      const int qrow = qbase + f * 16 + l15;
      const __hip_bfloat16* qptr = Q + (size_t)(b * S + qrow) * HD + h * D + l4 * 8;
      #pragma unroll
      for (int dc = 0; dc < 4; dc++) qf[f][dc] = *(const bf16x8*)(qptr + dc * 32);
    }

    f32x4 o[2][8];
    #pragma unroll
    for (int f = 0; f < 2; f++)
      #pragma unroll
      for (int nf = 0; nf < 8; nf++) o[f][nf] = (f32x4){0.f, 0.f, 0.f, 0.f};
    float mrun[2]  = {-1e30f, -1e30f};
    float llrun[2] = {0.f, 0.f};

    if (pass) __syncthreads();

    #pragma unroll
    for (int i = 0; i < 4; i++) {
      async_copy16(kSrc[i], (char*)Kt + stDst[i]);
      async_copy16(vSrc[i], (char*)Vt + stDst[i]);
    }

    int cur = 0;
    for (int t = 0; t < nt; t++) {
      __syncthreads();
      if (t + 1 < nt) {
        const int kv1 = (t + 1) * 64;
        #pragma unroll
        for (int i = 0; i < 4; i++) {
          async_copy16(kSrc[i] + (size_t)kv1 * KVD, (char*)Kt + (cur ^ 1) * 16384 + stDst[i]);
          async_copy16(vSrc[i] + kv1,               (char*)Vt + (cur ^ 1) * 16384 + stDst[i]);
        }
      }
      const char* ktb = (const char*)Kt + cur * 16384;
      const char* vtb = (const char*)Vt + cur * 16384;
      const int kv0 = t * 64;

      f32x4 s[2][4];
      #pragma unroll
      for (int f = 0; f < 2; f++)
        #pragma unroll
        for (int kg = 0; kg < 4; kg++) s[f][kg] = (f32x4){0.f, 0.f, 0.f, 0.f};
      __builtin_amdgcn_s_setprio(1);
      #pragma unroll
      for (int dc = 0; dc < 4; dc++) {
        #pragma unroll
        for (int kg = 0; kg < 4; kg++) {
          int key = kg * 16 + l15;
          int phys = (dc * 4 + l4) ^ (key & 7);
          bf16x8 kf = *(const bf16x8*)(ktb + key * 256 + phys * 16);
          s[0][kg] = __builtin_amdgcn_mfma_f32_16x16x32_bf16(kf, qf[0][dc], s[0][kg], 0, 0, 0);
          s[1][kg] = __builtin_amdgcn_mfma_f32_16x16x32_bf16(kf, qf[1][dc], s[1][kg], 0, 0, 0);
        }
      }
      __builtin_amdgcn_s_setprio(0);

      if (t >= nt - 2) {
        #pragma unroll
        for (int f = 0; f < 2; f++) {
          int q = qbase + f * 16 + l15;
          #pragma unroll
          for (int kg = 0; kg < 4; kg++)
            #pragma unroll
            for (int reg = 0; reg < 4; reg++)
              if (kv0 + kg * 16 + 4 * l4 + reg > q) s[f][kg][reg] = -1e30f;
        }
      }

      #pragma unroll
      for (int f = 0; f < 2; f++) {
        float pmax = -1e30f;
        #pragma unroll
        for (int kg = 0; kg < 4; kg++)
          #pragma unroll
          for (int reg = 0; reg < 4; reg++) pmax = fmaxf(pmax, s[f][kg][reg]);
        pmax = fmaxf(pmax, __shfl_xor(pmax, 16));
        pmax = fmaxf(pmax, __shfl_xor(pmax, 32));

        // T13 defer-max: rescale only if some row grew > THR=8
        float mn;
        if (__any(pmax > mrun[f] + 8.0f)) {
          mn = fmaxf(mrun[f], pmax);
          float alpha = __expf(mrun[f] - mn);
          mrun[f] = mn;
          llrun[f] *= alpha;
          float alpha_r[4];
          #pragma unroll
          for (int reg = 0; reg < 4; reg++)
            alpha_r[reg] = __shfl(alpha, (l & 48) + 4 * l4 + reg);
          #pragma unroll
          for (int nf = 0; nf < 8; nf++)
            #pragma unroll
            for (int reg = 0; reg < 4; reg++) o[f][nf][reg] *= alpha_r[reg];
        } else {
          mn = mrun[f];
        }

        float rs = 0.f;
        #pragma unroll
        for (int kg = 0; kg < 4; kg++)
          #pragma unroll
          for (int reg = 0; reg < 4; reg++) {
            float p = __expf(s[f][kg][reg] - mn);
            s[f][kg][reg] = p;
            rs += p;
          }
        rs += __shfl_xor(rs, 16);
        rs += __shfl_xor(rs, 32);
        llrun[f] += rs;

        #pragma unroll
        for (int kg = 0; kg < 4; kg++)
          #pragma unroll
          for (int p2 = 0; p2 < 2; p2++) {
            unsigned u = pack_bf16x2(s[f][kg][2 * p2], s[f][kg][2 * p2 + 1]);
            int slot16 = 2 * kg + (l4 >> 1);
            int inner = (8 * l4 + 4 * p2) & 15;
            *(unsigned*)(pbase + (f * 16 + l15) * 128 + ((slot16 ^ (l15 & 7)) * 16) + inner) = u;
          }
      }

      __builtin_amdgcn_s_setprio(1);
      #pragma unroll
      for (int half = 0; half < 2; half++) {
        int physp = (half * 4 + l4) ^ (l15 & 7);
        bf16x8 pa0 = *(const bf16x8*)(pbase + (0 * 16 + l15) * 128 + physp * 16);
        bf16x8 pa1 = *(const bf16x8*)(pbase + (1 * 16 + l15) * 128 + physp * 16);
        #pragma unroll
        for (int nf = 0; nf < 8; nf++) {
          int d = nf * 16 + l15;
          bf16x8 vf = *(const bf16x8*)(vtb + d * 128 + physp * 16);
          o[0][nf] = __builtin_amdgcn_mfma_f32_16x16x32_bf16(pa0, vf, o[0][nf], 0, 0, 0);
          o[1][nf] = __builtin_amdgcn_mfma_f32_16x16x32_bf16(pa1, vf, o[1][nf], 0, 0, 0);
        }
      }
      __builtin_amdgcn_s_setprio(0);
      cur ^= 1;
    }

    #pragma unroll
    for (int f = 0; f < 2; f++) {
      #pragma unroll
      for (int reg = 0; reg < 4; reg++) {
        float llr = __shfl(llrun[f], (l & 48) + 4 * l4 + reg);
        float inv = 1.0f / llr;
        int r = qbase + f * 16 + 4 * l4 + reg;
        __hip_bfloat16* optr = O + (size_t)(b * S + r) * HD + h * D + l15;
        #pragma unroll
        for (int nf = 0; nf < 8; nf++) optr[nf * 16] = __float2bfloat16(o[f][nf][reg] * inv);
      }
    }
  }
}

// ---------------------------------------------------------------------------
extern "C" void kernel_launch(void* const* d_in, const int* in_sizes, int n_in,
                              void* d_out, int out_size, void* d_ws, size_t ws_size,
                              hipStream_t stream) {
  const float* x    = (const float*)d_in[0];
  const float* fcos = (const float*)d_in[2];
  const float* fsin = (const float*)d_in[3];
  const float* wq   = (const float*)d_in[5];
  const float* wk   = (const float*)d_in[6];
  const float* wv   = (const float*)d_in[7];
  const float* wo   = (const float*)d_in[8];
  float* out = (float*)d_out;

  char* ws = (char*)d_ws;
  const size_t MB = 1024 * 1024;
  __hip_bfloat16* xb  = (__hip_bfloat16*)(ws + 0);        // 32MB; reused as ab
  __hip_bfloat16* wT  = (__hip_bfloat16*)(ws + 32 * MB);  // wqT; then vt; then woT
  __hip_bfloat16* wkT = (__hip_bfloat16*)(ws + 64 * MB);  // 8MB, contiguous with wvT
  __hip_bfloat16* wvT = (__hip_bfloat16*)(ws + 72 * MB);  // 8MB
  __hip_bfloat16* qb  = (__hip_bfloat16*)(ws + 80 * MB);
  __hip_bfloat16* kb  = (__hip_bfloat16*)(ws + 112 * MB);
  __hip_bfloat16* vb  = (__hip_bfloat16*)(ws + 120 * MB);
  __hip_bfloat16* ab  = xb;
  __hip_bfloat16* vt  = wT;

  const float qscale = 0.08838834764831845f;  // 1/sqrt(128)

  cvt_f32_bf16<<<16384, 256, 0, stream>>>(x, xb, 16777216);
  transpose_cvt<<<dim3(128, 128), dim3(32, 8), 0, stream>>>(wq, wT, 4096, 4096);
  transpose_cvt<<<dim3(32, 128), dim3(32, 8), 0, stream>>>(wk, wkT, 4096, 1024);
  transpose_cvt<<<dim3(32, 128), dim3(32, 8), 0, stream>>>(wv, wvT, 4096, 1024);

  gemm256<2><<<dim3(16, 16), 512, 0, stream>>>(xb, wT, nullptr, qb,
                                               4096, 4096, 4096, fcos, fsin, qscale);
  // fused K+V projection: BT = [wkT ; wvT] (contiguous), N=2048
  gemm_bt<3><<<dim3(16, 32), 256, 0, stream>>>(xb, wkT, nullptr, kb, vb,
                                               4096, 2048, 4096, fcos, fsin, 1.0f);

  transpose_v<<<dim3(64, 4, 16), dim3(32, 8), 0, stream>>>(vb, vt);

  attn_kernel<<<dim3(8, 32, 2), 256, 0, stream>>>(qb, kb, vt, ab);

  transpose_cvt<<<dim3(128, 128), dim3(32, 8), 0, stream>>>(wo, wT, 4096, 4096);
  gemm256<0><<<dim3(16, 16), 512, 0, stream>>>(ab, wT, out, nullptr,
                                               4096, 4096, 4096, nullptr, nullptr, 1.0f);
}